// Round 2
// baseline (675.549 us; speedup 1.0000x reference)
//
#include <hip/hip_runtime.h>
#include <hip/hip_bf16.h>

#define B_ 16
#define C_ 256
#define O_ 256
#define P_ 3136
#define E_ 8
#define HID_ 512
#define EPS_ 1e-5f

typedef __attribute__((ext_vector_type(8))) short bf16x8;
typedef __attribute__((ext_vector_type(4))) float f32x4;
typedef __hip_bfloat16 bf16;

__device__ __forceinline__ void gl2lds16(const bf16* g, bf16* l) {
  __builtin_amdgcn_global_load_lds((const __attribute__((address_space(1))) void*)g,
                                   (__attribute__((address_space(3))) void*)l,
                                   16, 0, 0);
}

// ---------------- prep: x NCHW fp32 -> NHWC bf16, fused global-avg-pool ----------------
__global__ __launch_bounds__(256) void xT_kernel(const float* __restrict__ x,
                                                 bf16* __restrict__ xT,
                                                 float* __restrict__ pooled) {
  __shared__ float tile[64][65];
  const int p0 = blockIdx.x * 64, c0 = blockIdx.y * 64, b = blockIdx.z;
  const int t = threadIdx.x;
#pragma unroll
  for (int j = 0; j < 16; ++j) {
    int idx = t + j * 256;
    int cl = idx >> 6, pl = idx & 63;
    tile[cl][pl] = x[(size_t)(b * C_ + c0 + cl) * P_ + p0 + pl];
  }
  __syncthreads();
#pragma unroll
  for (int j = 0; j < 16; ++j) {
    int idx = t + j * 256;
    int pl = idx >> 6, cl = idx & 63;
    xT[(size_t)(b * P_ + p0 + pl) * C_ + c0 + cl] = __float2bfloat16(tile[cl][pl]);
  }
  if (t < 64) {
    float s = 0.f;
#pragma unroll 8
    for (int pl = 0; pl < 64; ++pl) s += tile[t][pl];
    atomicAdd(&pooled[b * C_ + c0 + t], s * (1.0f / P_));
  }
}

// ---------------- prep: w1 [E][HID][C][3][3] -> [E][9][HID][C] bf16, BN1 scale folded ----
__global__ __launch_bounds__(256) void w1cvt_kernel(const float* __restrict__ w1,
                                                    const float* __restrict__ bn1_scale,
                                                    bf16* __restrict__ w1b) {
  const int eh = blockIdx.x;           // e*HID + hid
  const int e = eh >> 9, hid = eh & 511;
  __shared__ float buf[2304];
  const float* src = w1 + (size_t)eh * 2304;
  const int t = threadIdx.x;
  for (int i = t; i < 2304; i += 256) buf[i] = src[i];
  __syncthreads();
  const float inv = bn1_scale[eh] * (1.0f / sqrtf(1.0f + EPS_));
  for (int i = t; i < 2304; i += 256) {
    int rs = i >> 8, c = i & 255;
    w1b[((size_t)(e * 9 + rs) * HID_ + hid) * C_ + c] = __float2bfloat16(buf[c * 9 + rs] * inv);
  }
}

// ---------------- prep: w2 -> bf16 with BN2 scale folded ----------------
__global__ __launch_bounds__(256) void w2cvt_kernel(const float* __restrict__ w2,
                                                    const float* __restrict__ bn2_scale,
                                                    bf16* __restrict__ w2b) {
  const int i = blockIdx.x * 256 + threadIdx.x;   // E*O*HID = 1048576
  const int eo = i >> 9;
  w2b[i] = __float2bfloat16(w2[i] * (bn2_scale[eo] * (1.0f / sqrtf(1.0f + EPS_))));
}

// ---------------- prep: shared_w -> bf16 with BN scale folded ----------------
__global__ __launch_bounds__(256) void wshcvt_kernel(const float* __restrict__ wsh,
                                                     const float* __restrict__ sscale,
                                                     bf16* __restrict__ wshb) {
  const int i = blockIdx.x * 256 + threadIdx.x;   // O*C = 65536
  wshb[i] = __float2bfloat16(wsh[i] * (sscale[i >> 8] * (1.0f / sqrtf(1.0f + EPS_))));
}

// ---------------- router: logits/softmax/top2 + gated bias sums ----------------
__global__ __launch_bounds__(256) void router_kernel(const float* __restrict__ pooled,
                                                     const float* __restrict__ rw,
                                                     const float* __restrict__ rb,
                                                     const float* __restrict__ bn2_bias,
                                                     int* __restrict__ ridx,
                                                     float* __restrict__ rwt,
                                                     float* __restrict__ bsum) {
  __shared__ float lp[B_ * C_];
  __shared__ float llog[B_ * E_];
  __shared__ int lidx[B_ * 2];
  __shared__ float lw[B_ * 2];
  const int t = threadIdx.x;
  for (int i = t; i < B_ * C_; i += 256) lp[i] = pooled[i];
  __syncthreads();
  if (t < B_ * E_) {
    int b = t >> 3, e = t & 7;
    float s = rb[e];
    for (int c = 0; c < C_; ++c) s += lp[b * C_ + c] * rw[e * C_ + c];
    llog[t] = s;
  }
  __syncthreads();
  if (t < B_) {
    float pr[E_];
    float m = -1e30f;
    for (int e = 0; e < E_; ++e) { pr[e] = llog[t * E_ + e]; m = fmaxf(m, pr[e]); }
    float s = 0.f;
    for (int e = 0; e < E_; ++e) { pr[e] = __expf(pr[e] - m); s += pr[e]; }
    const float is = 1.f / s;
    for (int e = 0; e < E_; ++e) pr[e] *= is;
    int i0 = 0; float v0 = pr[0];
    for (int e = 1; e < E_; ++e) if (pr[e] > v0) { v0 = pr[e]; i0 = e; }
    int i1 = -1; float v1 = -1.f;
    for (int e = 0; e < E_; ++e) if (e != i0 && pr[e] > v1) { v1 = pr[e]; i1 = e; }
    const float wsum = 1.f / (v0 + v1);
    ridx[t * 2] = i0; ridx[t * 2 + 1] = i1;
    rwt[t * 2] = v0 * wsum; rwt[t * 2 + 1] = v1 * wsum;
    lidx[t * 2] = i0; lidx[t * 2 + 1] = i1;
    lw[t * 2] = v0 * wsum; lw[t * 2 + 1] = v1 * wsum;
  }
  __syncthreads();
  for (int i = t; i < B_ * O_; i += 256) {
    int b = i >> 8, o = i & 255;
    bsum[i] = lw[b * 2] * bn2_bias[lidx[b * 2] * O_ + o]
            + lw[b * 2 + 1] * bn2_bias[lidx[b * 2 + 1] * O_ + o];
  }
}

// ---------------- conv3x3 C->HID per routed (b,slot), implicit GEMM ----------------
// BM=128 pixels (25 tiles, 2% pad), BN=128 hid, BK=32. 4 waves, acc[4][4].
// Double-buffered LDS, prefetch-before-compute, one barrier per K-step.
// T2 swizzle: pre-swizzled global source + swizzled fragment read.
__global__ __launch_bounds__(256) void conv1_kernel(
    const bf16* __restrict__ xT, const bf16* __restrict__ w1b,
    const float* __restrict__ bn1_bias, const int* __restrict__ ridx,
    const float* __restrict__ rwt, const bf16* __restrict__ zp,
    bf16* __restrict__ h) {
  __shared__ __align__(16) bf16 ldsA[2][128 * 32];
  __shared__ __align__(16) bf16 ldsB[2][128 * 32];
  const int t = threadIdx.x;
  const int p0 = blockIdx.x * 128;
  const int h0 = blockIdx.y * 128;
  const int bs = blockIdx.z;
  const int b = bs >> 1;
  const int e = ridx[bs];
  const float wk = rwt[bs];

  const int lane = t & 63, wv = t >> 6;
  const int wm = wv >> 1, wn = wv & 1;
  const int r16 = lane & 15, q = lane >> 4;
  const int kslot = (q ^ (r16 & 3)) * 8;     // swizzled 16B slot for fragment reads

  const int rA = t >> 2;                      // staging row 0..63 (+64 in round 2)
  const int cSw = ((t & 3) ^ (rA & 3)) * 8;   // pre-swizzled source channel offset
  const int pA0 = p0 + rA, pA1 = pA0 + 64;
  const int yA0 = pA0 / 56, xA0 = pA0 - yA0 * 56;
  const int yA1 = pA1 / 56, xA1 = pA1 - yA1 * 56;
  const bool vP1 = (pA1 < P_);
  const bf16* xb = xT + (size_t)b * P_ * C_ + cSw;
  const bf16* wb = w1b + ((size_t)(e * 9) * HID_ + h0 + rA) * C_ + cSw;

  f32x4 acc[4][4] = {};

#define STAGE(buf, s) { \
    const int tap_ = (s) >> 3, c0k_ = ((s) & 7) * 32; \
    const int dr_ = tap_ / 3 - 1, dc_ = tap_ % 3 - 1; \
    const int off_ = dr_ * 56 + dc_; \
    const bool v0_ = ((unsigned)(yA0 + dr_) < 56u) & ((unsigned)(xA0 + dc_) < 56u); \
    const bool v1_ = vP1 & ((unsigned)(yA1 + dr_) < 56u) & ((unsigned)(xA1 + dc_) < 56u); \
    const bf16* a0_ = v0_ ? xb + (size_t)(pA0 + off_) * C_ + c0k_ : zp; \
    const bf16* a1_ = v1_ ? xb + (size_t)(pA1 + off_) * C_ + c0k_ : zp; \
    const bf16* b_ = wb + (size_t)(tap_ * HID_) * C_ + c0k_; \
    gl2lds16(a0_, ldsA[buf] + t * 8); \
    gl2lds16(a1_, ldsA[buf] + 2048 + t * 8); \
    gl2lds16(b_, ldsB[buf] + t * 8); \
    gl2lds16(b_ + 64 * C_, ldsB[buf] + 2048 + t * 8); \
  }

  STAGE(0, 0);
  __syncthreads();
  for (int s = 0; s < 72; ++s) {
    const int cur = s & 1;
    if (s < 71) STAGE(cur ^ 1, s + 1);
    const bf16* lA = ldsA[cur];
    const bf16* lB = ldsB[cur];
    bf16x8 af[4], bfr[4];
#pragma unroll
    for (int i = 0; i < 4; ++i) {
      af[i]  = *(const bf16x8*)(lA + (wm * 64 + i * 16 + r16) * 32 + kslot);
      bfr[i] = *(const bf16x8*)(lB + (wn * 64 + i * 16 + r16) * 32 + kslot);
    }
    __builtin_amdgcn_s_setprio(1);
#pragma unroll
    for (int mi = 0; mi < 4; ++mi)
#pragma unroll
      for (int ni = 0; ni < 4; ++ni)
        acc[mi][ni] = __builtin_amdgcn_mfma_f32_16x16x32_bf16(af[mi], bfr[ni], acc[mi][ni], 0, 0, 0);
    __builtin_amdgcn_s_setprio(0);
    if (s < 71) __syncthreads();
  }
#undef STAGE

  const int rowq = q * 4;
  float bias[4];
#pragma unroll
  for (int ni = 0; ni < 4; ++ni)
    bias[ni] = bn1_bias[e * HID_ + h0 + wn * 64 + ni * 16 + r16];
#pragma unroll
  for (int mi = 0; mi < 4; ++mi) {
#pragma unroll
    for (int i = 0; i < 4; ++i) {
      const int p = p0 + wm * 64 + mi * 16 + rowq + i;
      if (p < P_) {
        const size_t base = ((size_t)bs * P_ + p) * HID_;
#pragma unroll
        for (int ni = 0; ni < 4; ++ni) {
          const int hid = h0 + wn * 64 + ni * 16 + r16;
          float v = acc[mi][ni][i] + bias[ni];
          v = v / (1.f + __expf(-v));
          h[base + hid] = __float2bfloat16(wk * v);
        }
      }
    }
  }
}

// ---------------- combine: shared 1x1 (SiLU in-place) + both experts' 1x1 + bias + residual ----
// BM=128 o, BN=128 pixels (25 tiles), BK=32, K-sequence: shared(8) + e0(16) + e1(16).
__global__ __launch_bounds__(256) void combine_kernel(
    const bf16* __restrict__ xT, const bf16* __restrict__ h,
    const bf16* __restrict__ wshb, const bf16* __restrict__ w2b,
    const float* __restrict__ sbias, const float* __restrict__ bsum,
    const int* __restrict__ ridx, const float* __restrict__ x,
    const bf16* __restrict__ zp, float* __restrict__ out) {
  __shared__ __align__(16) bf16 ldsA[2][128 * 32];
  __shared__ __align__(16) bf16 ldsB[2][128 * 32];
  const int t = threadIdx.x;
  const int p0 = blockIdx.x * 128;
  const int o0 = blockIdx.y * 128;
  const int b = blockIdx.z;
  const int e0 = ridx[b * 2], e1 = ridx[b * 2 + 1];

  const int lane = t & 63, wv = t >> 6;
  const int wm = wv >> 1, wn = wv & 1;
  const int r16 = lane & 15, q = lane >> 4;
  const int kslot = (q ^ (r16 & 3)) * 8;

  const int rA = t >> 2;
  const int cSw = ((t & 3) ^ (rA & 3)) * 8;
  const int pB0 = p0 + rA, pB1 = pB0 + 64;
  const bool vB1 = (pB1 < P_);
  const bf16* shA = wshb + (size_t)(o0 + rA) * C_ + cSw;
  const bf16* xB = xT + (size_t)b * P_ * C_ + cSw;

  f32x4 acc[4][4] = {};

#define CSTAGE(buf, s) { \
    if ((s) < 8) { \
      const int c0k_ = (s) * 32; \
      gl2lds16(shA + c0k_, ldsA[buf] + t * 8); \
      gl2lds16(shA + 64 * C_ + c0k_, ldsA[buf] + 2048 + t * 8); \
      gl2lds16(xB + (size_t)pB0 * C_ + c0k_, ldsB[buf] + t * 8); \
      gl2lds16(vB1 ? xB + (size_t)pB1 * C_ + c0k_ : zp, ldsB[buf] + 2048 + t * 8); \
    } else { \
      const int ss_ = (s) - 8; const int slot_ = ss_ >> 4; const int c0k_ = (ss_ & 15) * 32; \
      const int ee_ = slot_ ? e1 : e0; \
      const bf16* wA_ = w2b + ((size_t)(ee_ * O_) + o0 + rA) * HID_ + c0k_ + cSw; \
      const bf16* hB_ = h + ((size_t)(b * 2 + slot_) * P_) * HID_ + c0k_ + cSw; \
      gl2lds16(wA_, ldsA[buf] + t * 8); \
      gl2lds16(wA_ + 64 * HID_, ldsA[buf] + 2048 + t * 8); \
      gl2lds16(hB_ + (size_t)pB0 * HID_, ldsB[buf] + t * 8); \
      gl2lds16(vB1 ? hB_ + (size_t)pB1 * HID_ : zp, ldsB[buf] + 2048 + t * 8); \
    } \
  }

  CSTAGE(0, 0);
  __syncthreads();
  for (int s = 0; s < 40; ++s) {
    const int cur = s & 1;
    if (s < 39) CSTAGE(cur ^ 1, s + 1);
    const bf16* lA = ldsA[cur];
    const bf16* lB = ldsB[cur];
    bf16x8 af[4], bfr[4];
#pragma unroll
    for (int i = 0; i < 4; ++i) {
      af[i]  = *(const bf16x8*)(lA + (wm * 64 + i * 16 + r16) * 32 + kslot);
      bfr[i] = *(const bf16x8*)(lB + (wn * 64 + i * 16 + r16) * 32 + kslot);
    }
    __builtin_amdgcn_s_setprio(1);
#pragma unroll
    for (int mi = 0; mi < 4; ++mi)
#pragma unroll
      for (int ni = 0; ni < 4; ++ni)
        acc[mi][ni] = __builtin_amdgcn_mfma_f32_16x16x32_bf16(af[mi], bfr[ni], acc[mi][ni], 0, 0, 0);
    __builtin_amdgcn_s_setprio(0);
    if (s == 7) {   // shared expert done: acc = silu(acc + shared_bias), experts accumulate on top
      const int rowq_ = q * 4;
#pragma unroll
      for (int mi = 0; mi < 4; ++mi)
#pragma unroll
        for (int i = 0; i < 4; ++i) {
          const float bias_ = sbias[o0 + wm * 64 + mi * 16 + rowq_ + i];
#pragma unroll
          for (int ni = 0; ni < 4; ++ni) {
            float v = acc[mi][ni][i] + bias_;
            acc[mi][ni][i] = v / (1.f + __expf(-v));
          }
        }
    }
    if (s < 39) __syncthreads();
  }
#undef CSTAGE

  const int rowq = q * 4;
#pragma unroll
  for (int mi = 0; mi < 4; ++mi) {
#pragma unroll
    for (int i = 0; i < 4; ++i) {
      const int o = o0 + wm * 64 + mi * 16 + rowq + i;
      const float bb = bsum[b * O_ + o];
      const size_t orow = (size_t)(b * O_ + o) * P_;
#pragma unroll
      for (int ni = 0; ni < 4; ++ni) {
        const int p = p0 + wn * 64 + ni * 16 + r16;
        if (p < P_) out[orow + p] = acc[mi][ni][i] + bb + x[orow + p];
      }
    }
  }
}

// ---------------- workspace layout ----------------
constexpr size_t SZ_XT = (size_t)B_ * P_ * C_ * 2;
constexpr size_t SZ_W1B = (size_t)E_ * 9 * HID_ * C_ * 2;
constexpr size_t SZ_W2B = (size_t)E_ * O_ * HID_ * 2;
constexpr size_t SZ_WSHB = (size_t)O_ * C_ * 2;
constexpr size_t SZ_POOL = (size_t)B_ * C_ * 4;
constexpr size_t SZ_BSUM = (size_t)B_ * O_ * 4;
constexpr size_t SZ_H = (size_t)B_ * 2 * P_ * HID_ * 2;

constexpr size_t OFF_XT = 0;
constexpr size_t OFF_W1B = OFF_XT + SZ_XT;
constexpr size_t OFF_W2B = OFF_W1B + SZ_W1B;
constexpr size_t OFF_WSHB = OFF_W2B + SZ_W2B;
constexpr size_t OFF_POOL = OFF_WSHB + SZ_WSHB;
constexpr size_t OFF_RIDX = OFF_POOL + SZ_POOL;   // 128 B
constexpr size_t OFF_RWT = OFF_RIDX + 128;        // 128 B
constexpr size_t OFF_BSUM = OFF_RWT + 128;
constexpr size_t OFF_ZERO = OFF_BSUM + SZ_BSUM;   // 1024 B zero page
constexpr size_t OFF_H = OFF_ZERO + 1024;

extern "C" void kernel_launch(void* const* d_in, const int* in_sizes, int n_in,
                              void* d_out, int out_size, void* d_ws, size_t ws_size,
                              hipStream_t stream) {
  const float* x = (const float*)d_in[0];
  const float* router_w = (const float*)d_in[1];
  const float* router_b = (const float*)d_in[2];
  const float* shared_w = (const float*)d_in[3];
  const float* shared_scale = (const float*)d_in[4];
  const float* shared_bias = (const float*)d_in[5];
  const float* w1 = (const float*)d_in[6];
  const float* bn1_scale = (const float*)d_in[7];
  const float* bn1_bias = (const float*)d_in[8];
  const float* w2 = (const float*)d_in[9];
  const float* bn2_scale = (const float*)d_in[10];
  const float* bn2_bias = (const float*)d_in[11];
  float* out = (float*)d_out;
  char* ws = (char*)d_ws;

  bf16* xT = (bf16*)(ws + OFF_XT);
  bf16* w1b = (bf16*)(ws + OFF_W1B);
  bf16* w2b = (bf16*)(ws + OFF_W2B);
  bf16* wshb = (bf16*)(ws + OFF_WSHB);
  float* pooled = (float*)(ws + OFF_POOL);
  int* ridx = (int*)(ws + OFF_RIDX);
  float* rwt = (float*)(ws + OFF_RWT);
  float* bsum = (float*)(ws + OFF_BSUM);
  bf16* zp = (bf16*)(ws + OFF_ZERO);
  bf16* h = (bf16*)(ws + OFF_H);

  hipMemsetAsync(ws + OFF_POOL, 0, SZ_POOL, stream);
  hipMemsetAsync(ws + OFF_ZERO, 0, 1024, stream);

  xT_kernel<<<dim3(49, 4, 16), 256, 0, stream>>>(x, xT, pooled);
  w1cvt_kernel<<<E_ * HID_, 256, 0, stream>>>(w1, bn1_scale, w1b);
  w2cvt_kernel<<<(E_ * O_ * HID_) / 256, 256, 0, stream>>>(w2, bn2_scale, w2b);
  wshcvt_kernel<<<(O_ * C_) / 256, 256, 0, stream>>>(shared_w, shared_scale, wshb);
  router_kernel<<<1, 256, 0, stream>>>(pooled, router_w, router_b, bn2_bias, ridx, rwt, bsum);
  conv1_kernel<<<dim3(25, 4, 32), 256, 0, stream>>>(xT, w1b, bn1_bias, ridx, rwt, zp, h);
  combine_kernel<<<dim3(25, 2, 16), 256, 0, stream>>>(xT, h, wshb, w2b, shared_bias, bsum, ridx, x, zp, out);
}

// Round 3
// 628.899 us; speedup vs baseline: 1.0742x; 1.0742x over previous
//
#include <hip/hip_runtime.h>
#include <hip/hip_bf16.h>

#define B_ 16
#define C_ 256
#define O_ 256
#define P_ 3136
#define E_ 8
#define HID_ 512
#define EPS_ 1e-5f

typedef __attribute__((ext_vector_type(8))) short bf16x8;
typedef __attribute__((ext_vector_type(4))) float f32x4;
typedef __hip_bfloat16 bf16;

__device__ __forceinline__ void gl2lds16(const bf16* g, bf16* l) {
  __builtin_amdgcn_global_load_lds((const __attribute__((address_space(1))) void*)g,
                                   (__attribute__((address_space(3))) void*)l,
                                   16, 0, 0);
}

__device__ __forceinline__ f32x4 mfma16(bf16x8 a, bf16x8 b, f32x4 c) {
  return __builtin_amdgcn_mfma_f32_16x16x32_bf16(a, b, c, 0, 0, 0);
}

// ---------------- prep: x NCHW fp32 -> NHWC bf16, fused global-avg-pool ----------------
__global__ __launch_bounds__(256) void xT_kernel(const float* __restrict__ x,
                                                 bf16* __restrict__ xT,
                                                 float* __restrict__ pooled) {
  __shared__ float tile[64][65];
  const int p0 = blockIdx.x * 64, c0 = blockIdx.y * 64, b = blockIdx.z;
  const int t = threadIdx.x;
#pragma unroll
  for (int j = 0; j < 16; ++j) {
    int idx = t + j * 256;
    int cl = idx >> 6, pl = idx & 63;
    tile[cl][pl] = x[(size_t)(b * C_ + c0 + cl) * P_ + p0 + pl];
  }
  __syncthreads();
#pragma unroll
  for (int j = 0; j < 16; ++j) {
    int idx = t + j * 256;
    int pl = idx >> 6, cl = idx & 63;
    xT[(size_t)(b * P_ + p0 + pl) * C_ + c0 + cl] = __float2bfloat16(tile[cl][pl]);
  }
  if (t < 64) {
    float s = 0.f;
#pragma unroll 8
    for (int pl = 0; pl < 64; ++pl) s += tile[t][pl];
    atomicAdd(&pooled[b * C_ + c0 + t], s * (1.0f / P_));
  }
}

// ---------------- prep: w1 [E][HID][C][3][3] -> [E][9][HID][C] bf16, BN1 scale folded ----
__global__ __launch_bounds__(256) void w1cvt_kernel(const float* __restrict__ w1,
                                                    const float* __restrict__ bn1_scale,
                                                    bf16* __restrict__ w1b) {
  const int eh = blockIdx.x;           // e*HID + hid
  const int e = eh >> 9, hid = eh & 511;
  __shared__ float buf[2304];
  const float* src = w1 + (size_t)eh * 2304;
  const int t = threadIdx.x;
  for (int i = t; i < 2304; i += 256) buf[i] = src[i];
  __syncthreads();
  const float inv = bn1_scale[eh] * (1.0f / sqrtf(1.0f + EPS_));
  for (int i = t; i < 2304; i += 256) {
    int rs = i >> 8, c = i & 255;
    w1b[((size_t)(e * 9 + rs) * HID_ + hid) * C_ + c] = __float2bfloat16(buf[c * 9 + rs] * inv);
  }
}

// ---------------- prep: w2 -> bf16 with BN2 scale folded ----------------
__global__ __launch_bounds__(256) void w2cvt_kernel(const float* __restrict__ w2,
                                                    const float* __restrict__ bn2_scale,
                                                    bf16* __restrict__ w2b) {
  const int i = blockIdx.x * 256 + threadIdx.x;   // E*O*HID = 1048576
  const int eo = i >> 9;
  w2b[i] = __float2bfloat16(w2[i] * (bn2_scale[eo] * (1.0f / sqrtf(1.0f + EPS_))));
}

// ---------------- prep: shared_w -> bf16 with BN scale folded ----------------
__global__ __launch_bounds__(256) void wshcvt_kernel(const float* __restrict__ wsh,
                                                     const float* __restrict__ sscale,
                                                     bf16* __restrict__ wshb) {
  const int i = blockIdx.x * 256 + threadIdx.x;   // O*C = 65536
  wshb[i] = __float2bfloat16(wsh[i] * (sscale[i >> 8] * (1.0f / sqrtf(1.0f + EPS_))));
}

// ---------------- router: logits/softmax/top2 + gated bias sums ----------------
__global__ __launch_bounds__(256) void router_kernel(const float* __restrict__ pooled,
                                                     const float* __restrict__ rw,
                                                     const float* __restrict__ rb,
                                                     const float* __restrict__ bn2_bias,
                                                     int* __restrict__ ridx,
                                                     float* __restrict__ rwt,
                                                     float* __restrict__ bsum) {
  __shared__ float lp[B_ * C_];
  __shared__ float llog[B_ * E_];
  __shared__ int lidx[B_ * 2];
  __shared__ float lw[B_ * 2];
  const int t = threadIdx.x;
  for (int i = t; i < B_ * C_; i += 256) lp[i] = pooled[i];
  __syncthreads();
  if (t < B_ * E_) {
    int b = t >> 3, e = t & 7;
    float s = rb[e];
    for (int c = 0; c < C_; ++c) s += lp[b * C_ + c] * rw[e * C_ + c];
    llog[t] = s;
  }
  __syncthreads();
  if (t < B_) {
    float pr[E_];
    float m = -1e30f;
    for (int e = 0; e < E_; ++e) { pr[e] = llog[t * E_ + e]; m = fmaxf(m, pr[e]); }
    float s = 0.f;
    for (int e = 0; e < E_; ++e) { pr[e] = __expf(pr[e] - m); s += pr[e]; }
    const float is = 1.f / s;
    for (int e = 0; e < E_; ++e) pr[e] *= is;
    int i0 = 0; float v0 = pr[0];
    for (int e = 1; e < E_; ++e) if (pr[e] > v0) { v0 = pr[e]; i0 = e; }
    int i1 = -1; float v1 = -1.f;
    for (int e = 0; e < E_; ++e) if (e != i0 && pr[e] > v1) { v1 = pr[e]; i1 = e; }
    const float wsum = 1.f / (v0 + v1);
    ridx[t * 2] = i0; ridx[t * 2 + 1] = i1;
    rwt[t * 2] = v0 * wsum; rwt[t * 2 + 1] = v1 * wsum;
    lidx[t * 2] = i0; lidx[t * 2 + 1] = i1;
    lw[t * 2] = v0 * wsum; lw[t * 2 + 1] = v1 * wsum;
  }
  __syncthreads();
  for (int i = t; i < B_ * O_; i += 256) {
    int b = i >> 8, o = i & 255;
    bsum[i] = lw[b * 2] * bn2_bias[lidx[b * 2] * O_ + o]
            + lw[b * 2 + 1] * bn2_bias[lidx[b * 2 + 1] * O_ + o];
  }
}

// ---------------- conv3x3 C->HID per routed (b,slot), implicit GEMM ----------------
// BM=256 pixels, BN=128 hid, BK=64. 512 thr / 8 waves (4M x 2N), wave tile 64x64.
// 3-deep LDS pipeline with counted vmcnt(6) (T4): stage kt+2 into buffer last read
// at kt-1 (barrier-separated -> race-free). Swizzled LDS (slot ^= row&7, T2) via
// inverse-swizzled global source + swizzled ds_read. XCD-aware block mapping (T1).
__global__ __launch_bounds__(512, 2) void conv1_kernel(
    const bf16* __restrict__ xT, const bf16* __restrict__ w1b,
    const float* __restrict__ bn1_bias, const int* __restrict__ ridx,
    const float* __restrict__ rwt, const bf16* __restrict__ zp,
    bf16* __restrict__ h) {
  __shared__ __align__(16) bf16 ldsA[3][256 * 64];
  __shared__ __align__(16) bf16 ldsB[3][128 * 64];
  const int t = threadIdx.x;
  // grid = 1664 = 8 XCD * (4 bs * 52 tiles); each XCD owns 4 consecutive bs.
  const int bid = blockIdx.x;
  const int xcd = bid & 7, j = bid >> 3;
  const int bsl = j / 52, tile = j % 52;
  const int mt = tile % 13, nt = tile / 13;
  const int bs = xcd * 4 + bsl;
  const int p0 = mt * 256, h0 = nt * 128;
  const int b = bs >> 1;
  const int e = ridx[bs];
  const float wk = rwt[bs];

  const int lane = t & 63, wv = t >> 6;
  const int wm = wv >> 1, wn = wv & 1;          // 4M x 2N wave grid
  const int r16 = lane & 15, q = lane >> 4;

  // staging geometry: thread t covers row srow (64/round), 16B slot (t&7)
  const int srow = t >> 3;
  const int cho = ((t & 7) ^ (srow & 7)) * 8;   // inverse-swizzled source slot
  int pA[4], yA[4], xA[4];
#pragma unroll
  for (int r = 0; r < 4; ++r) {
    pA[r] = p0 + r * 64 + srow;
    yA[r] = pA[r] / 56;
    xA[r] = pA[r] - yA[r] * 56;
  }
  const bf16* xb = xT + (size_t)b * P_ * C_ + cho;
  const bf16* wb = w1b + ((size_t)(e * 9) * HID_ + h0 + srow) * C_ + cho;
  bf16* laT = &ldsA[0][0] + t * 8;
  bf16* lbT = &ldsB[0][0] + t * 8;

  auto STAGE = [&](int bf, int s) {
    const int tap = s >> 2, ck = (s & 3) * 64;
    const int dr = tap / 3 - 1, dc = tap % 3 - 1;
    const int off = dr * 56 + dc;
#pragma unroll
    for (int r = 0; r < 4; ++r) {
      const bool v = (pA[r] < P_) & ((unsigned)(yA[r] + dr) < 56u) & ((unsigned)(xA[r] + dc) < 56u);
      const bf16* sp = v ? xb + (size_t)(pA[r] + off) * C_ + ck : zp;
      gl2lds16(sp, laT + bf * 16384 + r * 4096);
    }
    const bf16* wsrc = wb + (size_t)tap * HID_ * C_ + ck;
    gl2lds16(wsrc, lbT + bf * 8192);
    gl2lds16(wsrc + 64 * C_, lbT + bf * 8192 + 4096);
  };

  f32x4 acc[4][4] = {};

  STAGE(0, 0);
  STAGE(1, 1);
  asm volatile("s_waitcnt vmcnt(6)" ::: "memory");
  __builtin_amdgcn_s_barrier();
  asm volatile("" ::: "memory");

  const int Abase = (wm * 64 + r16) * 64;
  const int Bbase = (wn * 64 + r16) * 64;
  const int sb0 = (q ^ (r16 & 7)) * 8;          // ks=0 swizzled slot
  const int sb1 = ((4 + q) ^ (r16 & 7)) * 8;    // ks=1
  int cb = 0;
  for (int kt = 0; kt < 36; ++kt) {
    if (kt < 34) {
      const int nbf = cb + 2 >= 3 ? cb - 1 : cb + 2;
      STAGE(nbf, kt + 2);
    }
    const bf16* lA = &ldsA[0][0] + cb * 16384;
    const bf16* lB = &ldsB[0][0] + cb * 8192;
    bf16x8 a0[4], a1[4], b0v[4], b1v[4];
#pragma unroll
    for (int i = 0; i < 4; ++i) {
      a0[i] = *(const bf16x8*)(lA + Abase + i * 1024 + sb0);
      a1[i] = *(const bf16x8*)(lA + Abase + i * 1024 + sb1);
      b0v[i] = *(const bf16x8*)(lB + Bbase + i * 1024 + sb0);
      b1v[i] = *(const bf16x8*)(lB + Bbase + i * 1024 + sb1);
    }
    __builtin_amdgcn_s_setprio(1);
#pragma unroll
    for (int mi = 0; mi < 4; ++mi)
#pragma unroll
      for (int ni = 0; ni < 4; ++ni) {
        acc[mi][ni] = mfma16(a0[mi], b0v[ni], acc[mi][ni]);
        acc[mi][ni] = mfma16(a1[mi], b1v[ni], acc[mi][ni]);
      }
    __builtin_amdgcn_s_setprio(0);
    if (kt < 35) {
      if (kt < 34) asm volatile("s_waitcnt vmcnt(6)" ::: "memory");
      else         asm volatile("s_waitcnt vmcnt(0)" ::: "memory");
      __builtin_amdgcn_s_barrier();
      asm volatile("" ::: "memory");
    }
    cb = cb + 1 >= 3 ? 0 : cb + 1;
  }

  const int rowq = q * 4;
  float bias[4];
#pragma unroll
  for (int ni = 0; ni < 4; ++ni)
    bias[ni] = bn1_bias[e * HID_ + h0 + wn * 64 + ni * 16 + r16];
#pragma unroll
  for (int mi = 0; mi < 4; ++mi) {
#pragma unroll
    for (int i = 0; i < 4; ++i) {
      const int p = p0 + wm * 64 + mi * 16 + rowq + i;
      if (p < P_) {
        const size_t base = ((size_t)bs * P_ + p) * HID_;
#pragma unroll
        for (int ni = 0; ni < 4; ++ni) {
          const int hid = h0 + wn * 64 + ni * 16 + r16;
          float v = acc[mi][ni][i] + bias[ni];
          v = v / (1.f + __expf(-v));
          h[base + hid] = __float2bfloat16(wk * v);
        }
      }
    }
  }
}

// ---------------- combine: shared 1x1 (in-register SiLU) + both experts + residual ----
// BM=256 o (full O), BN=128 pixels, BK=64. Same 3-deep counted-vmcnt template.
// K-sequence: shared (kt 0-3), e0 (kt 4-11), e1 (kt 12-19). SiLU after kt 3.
__global__ __launch_bounds__(512, 2) void combine_kernel(
    const bf16* __restrict__ xT, const bf16* __restrict__ h,
    const bf16* __restrict__ wshb, const bf16* __restrict__ w2b,
    const float* __restrict__ sbias, const float* __restrict__ bsum,
    const int* __restrict__ ridx, const float* __restrict__ x,
    const bf16* __restrict__ zp, float* __restrict__ out) {
  __shared__ __align__(16) bf16 ldsA[3][256 * 64];
  __shared__ __align__(16) bf16 ldsB[3][128 * 64];
  const int t = threadIdx.x;
  // grid = 400 = 8 XCD * (2 b * 25 p-tiles)
  const int bid = blockIdx.x;
  const int xcd = bid & 7, j = bid >> 3;
  const int bl = j / 25, pt = j % 25;
  const int b = xcd * 2 + bl;
  const int p0 = pt * 128;
  const int e0 = ridx[b * 2], e1 = ridx[b * 2 + 1];

  const int lane = t & 63, wv = t >> 6;
  const int wm = wv >> 1, wn = wv & 1;
  const int r16 = lane & 15, q = lane >> 4;

  const int srow = t >> 3;
  const int cho = ((t & 7) ^ (srow & 7)) * 8;
  int pB[2];
  pB[0] = p0 + srow;
  pB[1] = p0 + 64 + srow;
  const bf16* wshp = wshb + (size_t)srow * C_ + cho;
  const bf16* w2p0 = w2b + ((size_t)(e0 * O_) + srow) * HID_ + cho;
  const bf16* w2p1 = w2b + ((size_t)(e1 * O_) + srow) * HID_ + cho;
  const bf16* xp = xT + (size_t)b * P_ * C_ + cho;
  const bf16* hp0 = h + (size_t)(b * 2) * P_ * HID_ + cho;
  const bf16* hp1 = h + (size_t)(b * 2 + 1) * P_ * HID_ + cho;
  bf16* laT = &ldsA[0][0] + t * 8;
  bf16* lbT = &ldsB[0][0] + t * 8;

  auto CSTAGE = [&](int bf, int s) {
    if (s < 4) {
      const int ck = s * 64;
#pragma unroll
      for (int r = 0; r < 4; ++r)
        gl2lds16(wshp + (size_t)(r * 64) * C_ + ck, laT + bf * 16384 + r * 4096);
#pragma unroll
      for (int r = 0; r < 2; ++r) {
        const bf16* sp = (pB[r] < P_) ? xp + (size_t)pB[r] * C_ + ck : zp;
        gl2lds16(sp, lbT + bf * 8192 + r * 4096);
      }
    } else {
      const int ss = s - 4;
      const int sl = ss >> 3, ck = (ss & 7) * 64;
      const bf16* wa = sl ? w2p1 : w2p0;
      const bf16* hb = sl ? hp1 : hp0;
#pragma unroll
      for (int r = 0; r < 4; ++r)
        gl2lds16(wa + (size_t)(r * 64) * HID_ + ck, laT + bf * 16384 + r * 4096);
#pragma unroll
      for (int r = 0; r < 2; ++r) {
        const bf16* sp = (pB[r] < P_) ? hb + (size_t)pB[r] * HID_ + ck : zp;
        gl2lds16(sp, lbT + bf * 8192 + r * 4096);
      }
    }
  };

  const int rowq = q * 4;
  float sb_[4][4];
#pragma unroll
  for (int mi = 0; mi < 4; ++mi)
#pragma unroll
    for (int i = 0; i < 4; ++i)
      sb_[mi][i] = sbias[wm * 64 + mi * 16 + rowq + i];

  f32x4 acc[4][4] = {};

  CSTAGE(0, 0);
  CSTAGE(1, 1);
  asm volatile("s_waitcnt vmcnt(6)" ::: "memory");
  __builtin_amdgcn_s_barrier();
  asm volatile("" ::: "memory");

  const int Abase = (wm * 64 + r16) * 64;
  const int Bbase = (wn * 64 + r16) * 64;
  const int sb0 = (q ^ (r16 & 7)) * 8;
  const int sb1 = ((4 + q) ^ (r16 & 7)) * 8;
  int cb = 0;
  for (int kt = 0; kt < 20; ++kt) {
    if (kt < 18) {
      const int nbf = cb + 2 >= 3 ? cb - 1 : cb + 2;
      CSTAGE(nbf, kt + 2);
    }
    const bf16* lA = &ldsA[0][0] + cb * 16384;
    const bf16* lB = &ldsB[0][0] + cb * 8192;
    bf16x8 a0[4], a1[4], b0v[4], b1v[4];
#pragma unroll
    for (int i = 0; i < 4; ++i) {
      a0[i] = *(const bf16x8*)(lA + Abase + i * 1024 + sb0);
      a1[i] = *(const bf16x8*)(lA + Abase + i * 1024 + sb1);
      b0v[i] = *(const bf16x8*)(lB + Bbase + i * 1024 + sb0);
      b1v[i] = *(const bf16x8*)(lB + Bbase + i * 1024 + sb1);
    }
    __builtin_amdgcn_s_setprio(1);
#pragma unroll
    for (int mi = 0; mi < 4; ++mi)
#pragma unroll
      for (int ni = 0; ni < 4; ++ni) {
        acc[mi][ni] = mfma16(a0[mi], b0v[ni], acc[mi][ni]);
        acc[mi][ni] = mfma16(a1[mi], b1v[ni], acc[mi][ni]);
      }
    __builtin_amdgcn_s_setprio(0);
    if (kt == 3) {  // shared expert complete -> SiLU in-register; experts accumulate on top
#pragma unroll
      for (int mi = 0; mi < 4; ++mi)
#pragma unroll
        for (int i = 0; i < 4; ++i)
#pragma unroll
          for (int ni = 0; ni < 4; ++ni) {
            float v = acc[mi][ni][i] + sb_[mi][i];
            acc[mi][ni][i] = v / (1.f + __expf(-v));
          }
    }
    if (kt < 19) {
      if (kt < 18) asm volatile("s_waitcnt vmcnt(6)" ::: "memory");
      else         asm volatile("s_waitcnt vmcnt(0)" ::: "memory");
      __builtin_amdgcn_s_barrier();
      asm volatile("" ::: "memory");
    }
    cb = cb + 1 >= 3 ? 0 : cb + 1;
  }

#pragma unroll
  for (int mi = 0; mi < 4; ++mi) {
#pragma unroll
    for (int i = 0; i < 4; ++i) {
      const int o = wm * 64 + mi * 16 + rowq + i;
      const float bb = bsum[b * O_ + o];
      const size_t orow = (size_t)(b * O_ + o) * P_;
#pragma unroll
      for (int ni = 0; ni < 4; ++ni) {
        const int p = p0 + wn * 64 + ni * 16 + r16;
        if (p < P_) out[orow + p] = acc[mi][ni][i] + bb + x[orow + p];
      }
    }
  }
}

// ---------------- workspace layout ----------------
constexpr size_t SZ_XT = (size_t)B_ * P_ * C_ * 2;
constexpr size_t SZ_W1B = (size_t)E_ * 9 * HID_ * C_ * 2;
constexpr size_t SZ_W2B = (size_t)E_ * O_ * HID_ * 2;
constexpr size_t SZ_WSHB = (size_t)O_ * C_ * 2;
constexpr size_t SZ_POOL = (size_t)B_ * C_ * 4;
constexpr size_t SZ_BSUM = (size_t)B_ * O_ * 4;

constexpr size_t OFF_XT = 0;
constexpr size_t OFF_W1B = OFF_XT + SZ_XT;
constexpr size_t OFF_W2B = OFF_W1B + SZ_W1B;
constexpr size_t OFF_WSHB = OFF_W2B + SZ_W2B;
constexpr size_t OFF_POOL = OFF_WSHB + SZ_WSHB;
constexpr size_t OFF_RIDX = OFF_POOL + SZ_POOL;   // 128 B
constexpr size_t OFF_RWT = OFF_RIDX + 128;        // 128 B
constexpr size_t OFF_BSUM = OFF_RWT + 128;
constexpr size_t OFF_ZERO = OFF_BSUM + SZ_BSUM;   // 1024 B zero page
constexpr size_t OFF_H = OFF_ZERO + 1024;

extern "C" void kernel_launch(void* const* d_in, const int* in_sizes, int n_in,
                              void* d_out, int out_size, void* d_ws, size_t ws_size,
                              hipStream_t stream) {
  const float* x = (const float*)d_in[0];
  const float* router_w = (const float*)d_in[1];
  const float* router_b = (const float*)d_in[2];
  const float* shared_w = (const float*)d_in[3];
  const float* shared_scale = (const float*)d_in[4];
  const float* shared_bias = (const float*)d_in[5];
  const float* w1 = (const float*)d_in[6];
  const float* bn1_scale = (const float*)d_in[7];
  const float* bn1_bias = (const float*)d_in[8];
  const float* w2 = (const float*)d_in[9];
  const float* bn2_scale = (const float*)d_in[10];
  const float* bn2_bias = (const float*)d_in[11];
  float* out = (float*)d_out;
  char* ws = (char*)d_ws;

  bf16* xT = (bf16*)(ws + OFF_XT);
  bf16* w1b = (bf16*)(ws + OFF_W1B);
  bf16* w2b = (bf16*)(ws + OFF_W2B);
  bf16* wshb = (bf16*)(ws + OFF_WSHB);
  float* pooled = (float*)(ws + OFF_POOL);
  int* ridx = (int*)(ws + OFF_RIDX);
  float* rwt = (float*)(ws + OFF_RWT);
  float* bsum = (float*)(ws + OFF_BSUM);
  bf16* zp = (bf16*)(ws + OFF_ZERO);
  bf16* h = (bf16*)(ws + OFF_H);

  hipMemsetAsync(ws + OFF_POOL, 0, SZ_POOL, stream);
  hipMemsetAsync(ws + OFF_ZERO, 0, 1024, stream);

  xT_kernel<<<dim3(49, 4, 16), 256, 0, stream>>>(x, xT, pooled);
  w1cvt_kernel<<<E_ * HID_, 256, 0, stream>>>(w1, bn1_scale, w1b);
  w2cvt_kernel<<<(E_ * O_ * HID_) / 256, 256, 0, stream>>>(w2, bn2_scale, w2b);
  wshcvt_kernel<<<(O_ * C_) / 256, 256, 0, stream>>>(shared_w, shared_scale, wshb);
  router_kernel<<<1, 256, 0, stream>>>(pooled, router_w, router_b, bn2_bias, ridx, rwt, bsum);
  conv1_kernel<<<1664, 512, 0, stream>>>(xT, w1b, bn1_bias, ridx, rwt, zp, h);
  combine_kernel<<<400, 512, 0, stream>>>(xT, h, wshb, w2b, shared_bias, bsum, ridx, x, zp, out);
}

// Round 4
// 592.867 us; speedup vs baseline: 1.1395x; 1.0608x over previous
//
#include <hip/hip_runtime.h>
#include <hip/hip_bf16.h>

#define B_ 16
#define C_ 256
#define O_ 256
#define P_ 3136
#define E_ 8
#define HID_ 512
#define EPS_ 1e-5f

typedef __attribute__((ext_vector_type(8))) short bf16x8;
typedef __attribute__((ext_vector_type(4))) float f32x4;
typedef __hip_bfloat16 bf16;

__device__ __forceinline__ void gl2lds16(const bf16* g, bf16* l) {
  __builtin_amdgcn_global_load_lds((const __attribute__((address_space(1))) void*)g,
                                   (__attribute__((address_space(3))) void*)l,
                                   16, 0, 0);
}

__device__ __forceinline__ f32x4 mfma16(bf16x8 a, bf16x8 b, f32x4 c) {
  return __builtin_amdgcn_mfma_f32_16x16x32_bf16(a, b, c, 0, 0, 0);
}

// ---------------- prep: x NCHW fp32 -> NHWC bf16, fused global-avg-pool ----------------
__global__ __launch_bounds__(256) void xT_kernel(const float* __restrict__ x,
                                                 bf16* __restrict__ xT,
                                                 float* __restrict__ pooled) {
  __shared__ float tile[64][65];
  const int p0 = blockIdx.x * 64, c0 = blockIdx.y * 64, b = blockIdx.z;
  const int t = threadIdx.x;
#pragma unroll
  for (int j = 0; j < 16; ++j) {
    int idx = t + j * 256;
    int cl = idx >> 6, pl = idx & 63;
    tile[cl][pl] = x[(size_t)(b * C_ + c0 + cl) * P_ + p0 + pl];
  }
  __syncthreads();
#pragma unroll
  for (int j = 0; j < 16; ++j) {
    int idx = t + j * 256;
    int pl = idx >> 6, cl = idx & 63;
    xT[(size_t)(b * P_ + p0 + pl) * C_ + c0 + cl] = __float2bfloat16(tile[cl][pl]);
  }
  if (t < 64) {
    float s = 0.f;
#pragma unroll 8
    for (int pl = 0; pl < 64; ++pl) s += tile[t][pl];
    atomicAdd(&pooled[b * C_ + c0 + t], s * (1.0f / P_));
  }
}

// ---------------- prep: w1 [E][HID][C][3][3] -> [E][9][HID][C] bf16, BN1 scale folded ----
__global__ __launch_bounds__(256) void w1cvt_kernel(const float* __restrict__ w1,
                                                    const float* __restrict__ bn1_scale,
                                                    bf16* __restrict__ w1b) {
  const int eh = blockIdx.x;           // e*HID + hid
  const int e = eh >> 9, hid = eh & 511;
  __shared__ float buf[2304];
  const float* src = w1 + (size_t)eh * 2304;
  const int t = threadIdx.x;
  for (int i = t; i < 2304; i += 256) buf[i] = src[i];
  __syncthreads();
  const float inv = bn1_scale[eh] * (1.0f / sqrtf(1.0f + EPS_));
  for (int i = t; i < 2304; i += 256) {
    int rs = i >> 8, c = i & 255;
    w1b[((size_t)(e * 9 + rs) * HID_ + hid) * C_ + c] = __float2bfloat16(buf[c * 9 + rs] * inv);
  }
}

// ---------------- prep: w2 -> bf16 with BN2 scale folded ----------------
__global__ __launch_bounds__(256) void w2cvt_kernel(const float* __restrict__ w2,
                                                    const float* __restrict__ bn2_scale,
                                                    bf16* __restrict__ w2b) {
  const int i = blockIdx.x * 256 + threadIdx.x;   // E*O*HID = 1048576
  const int eo = i >> 9;
  w2b[i] = __float2bfloat16(w2[i] * (bn2_scale[eo] * (1.0f / sqrtf(1.0f + EPS_))));
}

// ---------------- prep: shared_w -> bf16 with BN scale folded ----------------
__global__ __launch_bounds__(256) void wshcvt_kernel(const float* __restrict__ wsh,
                                                     const float* __restrict__ sscale,
                                                     bf16* __restrict__ wshb) {
  const int i = blockIdx.x * 256 + threadIdx.x;   // O*C = 65536
  wshb[i] = __float2bfloat16(wsh[i] * (sscale[i >> 8] * (1.0f / sqrtf(1.0f + EPS_))));
}

// ---------------- router: logits/softmax/top2 + gated bias sums ----------------
__global__ __launch_bounds__(256) void router_kernel(const float* __restrict__ pooled,
                                                     const float* __restrict__ rw,
                                                     const float* __restrict__ rb,
                                                     const float* __restrict__ bn2_bias,
                                                     int* __restrict__ ridx,
                                                     float* __restrict__ rwt,
                                                     float* __restrict__ bsum) {
  __shared__ float lp[B_ * C_];
  __shared__ float llog[B_ * E_];
  __shared__ int lidx[B_ * 2];
  __shared__ float lw[B_ * 2];
  const int t = threadIdx.x;
  for (int i = t; i < B_ * C_; i += 256) lp[i] = pooled[i];
  __syncthreads();
  if (t < B_ * E_) {
    int b = t >> 3, e = t & 7;
    float s = rb[e];
    for (int c = 0; c < C_; ++c) s += lp[b * C_ + c] * rw[e * C_ + c];
    llog[t] = s;
  }
  __syncthreads();
  if (t < B_) {
    float pr[E_];
    float m = -1e30f;
    for (int e = 0; e < E_; ++e) { pr[e] = llog[t * E_ + e]; m = fmaxf(m, pr[e]); }
    float s = 0.f;
    for (int e = 0; e < E_; ++e) { pr[e] = __expf(pr[e] - m); s += pr[e]; }
    const float is = 1.f / s;
    for (int e = 0; e < E_; ++e) pr[e] *= is;
    int i0 = 0; float v0 = pr[0];
    for (int e = 1; e < E_; ++e) if (pr[e] > v0) { v0 = pr[e]; i0 = e; }
    int i1 = -1; float v1 = -1.f;
    for (int e = 0; e < E_; ++e) if (e != i0 && pr[e] > v1) { v1 = pr[e]; i1 = e; }
    const float wsum = 1.f / (v0 + v1);
    ridx[t * 2] = i0; ridx[t * 2 + 1] = i1;
    rwt[t * 2] = v0 * wsum; rwt[t * 2 + 1] = v1 * wsum;
    lidx[t * 2] = i0; lidx[t * 2 + 1] = i1;
    lw[t * 2] = v0 * wsum; lw[t * 2 + 1] = v1 * wsum;
  }
  __syncthreads();
  for (int i = t; i < B_ * O_; i += 256) {
    int b = i >> 8, o = i & 255;
    bsum[i] = lw[b * 2] * bn2_bias[lidx[b * 2] * O_ + o]
            + lw[b * 2 + 1] * bn2_bias[lidx[b * 2 + 1] * O_ + o];
  }
}

// ---------------- conv3x3 C->HID per routed (b,slot), implicit GEMM ----------------
// BM=128 px, BN=128 hid, BK=32. 256 thr / 4 waves (2x2), wave tile 64x64.
// 3-deep LDS (48 KB -> 3 blocks/CU), counted vmcnt(4), 1 barrier/kt.
// T2 swizzle for BK=32: slot = kslot ^ ((row>>1)&3) (2-way per 16-lane phase = free).
__global__ __launch_bounds__(256, 3) void conv1_kernel(
    const bf16* __restrict__ xT, const bf16* __restrict__ w1b,
    const float* __restrict__ bn1_bias, const int* __restrict__ ridx,
    const float* __restrict__ rwt, const bf16* __restrict__ zp,
    bf16* __restrict__ h) {
  __shared__ __align__(16) bf16 ldsA[3][4096];   // [buf][128 rows x 32 ch]
  __shared__ __align__(16) bf16 ldsB[3][4096];
  const int t = threadIdx.x;
  // grid = 3200 = 8 XCD * (4 bs * 100 tiles); each XCD owns 4 consecutive bs.
  const int bid = blockIdx.x;
  const int xcd = bid & 7, j = bid >> 3;
  const int bsl = j / 100, j2 = j % 100;
  const int mt = j2 % 25, nt = j2 / 25;
  const int bs = xcd * 4 + bsl;
  const int p0 = mt * 128, h0 = nt * 128;
  const int b = bs >> 1;
  const int e = ridx[bs];
  const float wk = rwt[bs];

  const int lane = t & 63, wv = t >> 6;
  const int wm = wv >> 1, wn = wv & 1;           // 2x2 wave grid
  const int r16 = lane & 15, q = lane >> 4;
  const int koffA = ((q ^ ((r16 >> 1) & 3)) * 8);  // swizzled k-slot (bf16 units)

  // staging: thread t -> row srow (0..63; +64 in round 2), linear slot t&3
  const int srow = t >> 2;
  const int cho = (((t & 3) ^ ((srow >> 1) & 3)) * 8);  // inverse-swizzled source ch
  const int pA0 = p0 + srow, pA1 = pA0 + 64;
  const int yA0 = pA0 / 56, xA0 = pA0 - yA0 * 56;
  const int yA1 = pA1 / 56, xA1 = pA1 - yA1 * 56;
  const bf16* xb = xT + (size_t)b * P_ * C_ + cho;
  const bf16* wb = w1b + ((size_t)(e * 9) * HID_ + h0 + srow) * C_ + cho;
  bf16* laT = &ldsA[0][0] + t * 8;
  bf16* lbT = &ldsB[0][0] + t * 8;

  auto STAGE = [&](int bf, int s) {
    const int tap = s >> 3, ck = (s & 7) * 32;
    const int dr = ((tap * 11) >> 5) - 1;
    const int dc = tap - (dr + 1) * 3 - 1;
    const int off = dr * 56 + dc;
    const bool v0 = (pA0 < P_) & ((unsigned)(yA0 + dr) < 56u) & ((unsigned)(xA0 + dc) < 56u);
    const bool v1 = (pA1 < P_) & ((unsigned)(yA1 + dr) < 56u) & ((unsigned)(xA1 + dc) < 56u);
    gl2lds16(v0 ? xb + (size_t)(pA0 + off) * C_ + ck : zp, laT + bf * 4096);
    gl2lds16(v1 ? xb + (size_t)(pA1 + off) * C_ + ck : zp, laT + bf * 4096 + 2048);
    const bf16* wsrc = wb + (size_t)tap * (HID_ * C_) + ck;
    gl2lds16(wsrc, lbT + bf * 4096);
    gl2lds16(wsrc + 64 * C_, lbT + bf * 4096 + 2048);
  };

  f32x4 acc[4][4] = {};

  STAGE(0, 0);
  STAGE(1, 1);
  asm volatile("s_waitcnt vmcnt(4)" ::: "memory");
  __builtin_amdgcn_s_barrier();
  asm volatile("" ::: "memory");

  const int Abase = (wm * 64 + r16) * 32 + koffA;
  const int Bbase = (wn * 64 + r16) * 32 + koffA;
  int cb = 0;
  for (int kt = 0; kt < 72; ++kt) {
    if (kt < 70) {
      const int nbf = cb + 2 >= 3 ? cb - 1 : cb + 2;
      STAGE(nbf, kt + 2);
    }
    const bf16* lA = &ldsA[0][0] + cb * 4096;
    const bf16* lB = &ldsB[0][0] + cb * 4096;
    bf16x8 af[4], bf[4];
#pragma unroll
    for (int i = 0; i < 4; ++i) {
      af[i] = *(const bf16x8*)(lA + Abase + i * 512);
      bf[i] = *(const bf16x8*)(lB + Bbase + i * 512);
    }
    __builtin_amdgcn_s_setprio(1);
#pragma unroll
    for (int mi = 0; mi < 4; ++mi)
#pragma unroll
      for (int ni = 0; ni < 4; ++ni)
        acc[mi][ni] = mfma16(af[mi], bf[ni], acc[mi][ni]);
    __builtin_amdgcn_s_setprio(0);
    if (kt < 71) {
      if (kt < 70) asm volatile("s_waitcnt vmcnt(4)" ::: "memory");
      else         asm volatile("s_waitcnt vmcnt(0)" ::: "memory");
      __builtin_amdgcn_s_barrier();
      asm volatile("" ::: "memory");
    }
    cb = cb + 1 >= 3 ? 0 : cb + 1;
  }

  const int rowq = q * 4;
  float bias[4];
#pragma unroll
  for (int ni = 0; ni < 4; ++ni)
    bias[ni] = bn1_bias[e * HID_ + h0 + wn * 64 + ni * 16 + r16];
#pragma unroll
  for (int mi = 0; mi < 4; ++mi) {
#pragma unroll
    for (int i = 0; i < 4; ++i) {
      const int p = p0 + wm * 64 + mi * 16 + rowq + i;
      if (p < P_) {
        const size_t base = ((size_t)bs * P_ + p) * HID_;
#pragma unroll
        for (int ni = 0; ni < 4; ++ni) {
          const int hid = h0 + wn * 64 + ni * 16 + r16;
          float v = acc[mi][ni][i] + bias[ni];
          v = v / (1.f + __expf(-v));
          h[base + hid] = __float2bfloat16(wk * v);
        }
      }
    }
  }
}

// ---------------- combine: shared 1x1 (in-register SiLU) + both experts + residual ----
// BM=128 o, BN=128 px, BK=32, same 3-deep counted-vmcnt template.
// K-sequence: shared kt 0-7, e0 kt 8-23, e1 kt 24-39. SiLU after kt 7.
__global__ __launch_bounds__(256, 3) void combine_kernel(
    const bf16* __restrict__ xT, const bf16* __restrict__ h,
    const bf16* __restrict__ wshb, const bf16* __restrict__ w2b,
    const float* __restrict__ sbias, const float* __restrict__ bsum,
    const int* __restrict__ ridx, const float* __restrict__ x,
    const bf16* __restrict__ zp, float* __restrict__ out) {
  __shared__ __align__(16) bf16 ldsA[3][4096];
  __shared__ __align__(16) bf16 ldsB[3][4096];
  const int t = threadIdx.x;
  // grid = 800 = 8 XCD * (2 b * 50 tiles)
  const int bid = blockIdx.x;
  const int xcd = bid & 7, j = bid >> 3;
  const int bl = j / 50, j2 = j % 50;
  const int ot = j2 / 25, pt = j2 % 25;
  const int b = xcd * 2 + bl;
  const int o0 = ot * 128, p0 = pt * 128;
  const int e0 = ridx[b * 2], e1 = ridx[b * 2 + 1];

  const int lane = t & 63, wv = t >> 6;
  const int wm = wv >> 1, wn = wv & 1;
  const int r16 = lane & 15, q = lane >> 4;
  const int koffA = ((q ^ ((r16 >> 1) & 3)) * 8);

  const int srow = t >> 2;
  const int cho = (((t & 3) ^ ((srow >> 1) & 3)) * 8);
  const int pB0 = p0 + srow, pB1 = pB0 + 64;
  const bool vB0 = (pB0 < P_), vB1 = (pB1 < P_);
  const bf16* wshp = wshb + (size_t)(o0 + srow) * C_ + cho;
  const bf16* w2p0 = w2b + ((size_t)(e0 * O_) + o0 + srow) * HID_ + cho;
  const bf16* w2p1 = w2b + ((size_t)(e1 * O_) + o0 + srow) * HID_ + cho;
  const bf16* xp = xT + (size_t)b * P_ * C_ + cho;
  const bf16* hp0 = h + (size_t)(b * 2) * P_ * HID_ + cho;
  const bf16* hp1 = h + (size_t)(b * 2 + 1) * P_ * HID_ + cho;
  bf16* laT = &ldsA[0][0] + t * 8;
  bf16* lbT = &ldsB[0][0] + t * 8;

  auto CSTAGE = [&](int bf, int s) {
    const bf16 *a0, *a1, *b0, *b1;
    if (s < 8) {
      const int ck = s * 32;
      a0 = wshp + ck;
      a1 = wshp + 64 * C_ + ck;
      b0 = vB0 ? xp + (size_t)pB0 * C_ + ck : zp;
      b1 = vB1 ? xp + (size_t)pB1 * C_ + ck : zp;
    } else {
      const int ss = s - 8;
      const int sl = ss >> 4, ck = (ss & 15) * 32;
      const bf16* wa = sl ? w2p1 : w2p0;
      const bf16* hb = sl ? hp1 : hp0;
      a0 = wa + ck;
      a1 = wa + 64 * HID_ + ck;
      b0 = vB0 ? hb + (size_t)pB0 * HID_ + ck : zp;
      b1 = vB1 ? hb + (size_t)pB1 * HID_ + ck : zp;
    }
    gl2lds16(a0, laT + bf * 4096);
    gl2lds16(a1, laT + bf * 4096 + 2048);
    gl2lds16(b0, lbT + bf * 4096);
    gl2lds16(b1, lbT + bf * 4096 + 2048);
  };

  const int rowq = q * 4;
  float sb_[4][4];
#pragma unroll
  for (int mi = 0; mi < 4; ++mi)
#pragma unroll
    for (int i = 0; i < 4; ++i)
      sb_[mi][i] = sbias[o0 + wm * 64 + mi * 16 + rowq + i];

  f32x4 acc[4][4] = {};

  CSTAGE(0, 0);
  CSTAGE(1, 1);
  asm volatile("s_waitcnt vmcnt(4)" ::: "memory");
  __builtin_amdgcn_s_barrier();
  asm volatile("" ::: "memory");

  const int Abase = (wm * 64 + r16) * 32 + koffA;
  const int Bbase = (wn * 64 + r16) * 32 + koffA;
  int cb = 0;
  for (int kt = 0; kt < 40; ++kt) {
    if (kt < 38) {
      const int nbf = cb + 2 >= 3 ? cb - 1 : cb + 2;
      CSTAGE(nbf, kt + 2);
    }
    const bf16* lA = &ldsA[0][0] + cb * 4096;
    const bf16* lB = &ldsB[0][0] + cb * 4096;
    bf16x8 af[4], bf[4];
#pragma unroll
    for (int i = 0; i < 4; ++i) {
      af[i] = *(const bf16x8*)(lA + Abase + i * 512);
      bf[i] = *(const bf16x8*)(lB + Bbase + i * 512);
    }
    __builtin_amdgcn_s_setprio(1);
#pragma unroll
    for (int mi = 0; mi < 4; ++mi)
#pragma unroll
      for (int ni = 0; ni < 4; ++ni)
        acc[mi][ni] = mfma16(af[mi], bf[ni], acc[mi][ni]);
    __builtin_amdgcn_s_setprio(0);
    if (kt == 7) {  // shared expert complete -> SiLU in-register; experts accumulate on top
#pragma unroll
      for (int mi = 0; mi < 4; ++mi)
#pragma unroll
        for (int i = 0; i < 4; ++i)
#pragma unroll
          for (int ni = 0; ni < 4; ++ni) {
            float v = acc[mi][ni][i] + sb_[mi][i];
            acc[mi][ni][i] = v / (1.f + __expf(-v));
          }
    }
    if (kt < 39) {
      if (kt < 38) asm volatile("s_waitcnt vmcnt(4)" ::: "memory");
      else         asm volatile("s_waitcnt vmcnt(0)" ::: "memory");
      __builtin_amdgcn_s_barrier();
      asm volatile("" ::: "memory");
    }
    cb = cb + 1 >= 3 ? 0 : cb + 1;
  }

#pragma unroll
  for (int mi = 0; mi < 4; ++mi) {
#pragma unroll
    for (int i = 0; i < 4; ++i) {
      const int o = o0 + wm * 64 + mi * 16 + rowq + i;
      const float bb = bsum[b * O_ + o];
      const size_t orow = (size_t)(b * O_ + o) * P_;
#pragma unroll
      for (int ni = 0; ni < 4; ++ni) {
        const int p = p0 + wn * 64 + ni * 16 + r16;
        if (p < P_) out[orow + p] = acc[mi][ni][i] + bb + x[orow + p];
      }
    }
  }
}

// ---------------- workspace layout ----------------
constexpr size_t SZ_XT = (size_t)B_ * P_ * C_ * 2;
constexpr size_t SZ_W1B = (size_t)E_ * 9 * HID_ * C_ * 2;
constexpr size_t SZ_W2B = (size_t)E_ * O_ * HID_ * 2;
constexpr size_t SZ_WSHB = (size_t)O_ * C_ * 2;
constexpr size_t SZ_POOL = (size_t)B_ * C_ * 4;
constexpr size_t SZ_BSUM = (size_t)B_ * O_ * 4;

constexpr size_t OFF_XT = 0;
constexpr size_t OFF_W1B = OFF_XT + SZ_XT;
constexpr size_t OFF_W2B = OFF_W1B + SZ_W1B;
constexpr size_t OFF_WSHB = OFF_W2B + SZ_W2B;
constexpr size_t OFF_POOL = OFF_WSHB + SZ_WSHB;
constexpr size_t OFF_RIDX = OFF_POOL + SZ_POOL;   // 128 B
constexpr size_t OFF_RWT = OFF_RIDX + 128;        // 128 B
constexpr size_t OFF_BSUM = OFF_RWT + 128;
constexpr size_t OFF_ZERO = OFF_BSUM + SZ_BSUM;   // 1024 B zero page
constexpr size_t OFF_H = OFF_ZERO + 1024;

extern "C" void kernel_launch(void* const* d_in, const int* in_sizes, int n_in,
                              void* d_out, int out_size, void* d_ws, size_t ws_size,
                              hipStream_t stream) {
  const float* x = (const float*)d_in[0];
  const float* router_w = (const float*)d_in[1];
  const float* router_b = (const float*)d_in[2];
  const float* shared_w = (const float*)d_in[3];
  const float* shared_scale = (const float*)d_in[4];
  const float* shared_bias = (const float*)d_in[5];
  const float* w1 = (const float*)d_in[6];
  const float* bn1_scale = (const float*)d_in[7];
  const float* bn1_bias = (const float*)d_in[8];
  const float* w2 = (const float*)d_in[9];
  const float* bn2_scale = (const float*)d_in[10];
  const float* bn2_bias = (const float*)d_in[11];
  float* out = (float*)d_out;
  char* ws = (char*)d_ws;

  bf16* xT = (bf16*)(ws + OFF_XT);
  bf16* w1b = (bf16*)(ws + OFF_W1B);
  bf16* w2b = (bf16*)(ws + OFF_W2B);
  bf16* wshb = (bf16*)(ws + OFF_WSHB);
  float* pooled = (float*)(ws + OFF_POOL);
  int* ridx = (int*)(ws + OFF_RIDX);
  float* rwt = (float*)(ws + OFF_RWT);
  float* bsum = (float*)(ws + OFF_BSUM);
  bf16* zp = (bf16*)(ws + OFF_ZERO);
  bf16* h = (bf16*)(ws + OFF_H);

  hipMemsetAsync(ws + OFF_POOL, 0, SZ_POOL, stream);
  hipMemsetAsync(ws + OFF_ZERO, 0, 1024, stream);

  xT_kernel<<<dim3(49, 4, 16), 256, 0, stream>>>(x, xT, pooled);
  w1cvt_kernel<<<E_ * HID_, 256, 0, stream>>>(w1, bn1_scale, w1b);
  w2cvt_kernel<<<(E_ * O_ * HID_) / 256, 256, 0, stream>>>(w2, bn2_scale, w2b);
  wshcvt_kernel<<<(O_ * C_) / 256, 256, 0, stream>>>(shared_w, shared_scale, wshb);
  router_kernel<<<1, 256, 0, stream>>>(pooled, router_w, router_b, bn2_bias, ridx, rwt, bsum);
  conv1_kernel<<<3200, 256, 0, stream>>>(xT, w1b, bn1_bias, ridx, rwt, zp, h);
  combine_kernel<<<800, 256, 0, stream>>>(xT, h, wshb, w2b, shared_bias, bsum, ridx, x, zp, out);
}

// Round 5
// 559.557 us; speedup vs baseline: 1.2073x; 1.0595x over previous
//
#include <hip/hip_runtime.h>
#include <hip/hip_bf16.h>

#define B_ 16
#define C_ 256
#define O_ 256
#define P_ 3136
#define E_ 8
#define HID_ 512
#define EPS_ 1e-5f

typedef __attribute__((ext_vector_type(8))) short bf16x8;
typedef __attribute__((ext_vector_type(4))) float f32x4;
typedef __hip_bfloat16 bf16;

__device__ __forceinline__ void gl2lds16(const bf16* g, bf16* l) {
  __builtin_amdgcn_global_load_lds((const __attribute__((address_space(1))) void*)g,
                                   (__attribute__((address_space(3))) void*)l,
                                   16, 0, 0);
}

__device__ __forceinline__ f32x4 mfma16(bf16x8 a, bf16x8 b, f32x4 c) {
  return __builtin_amdgcn_mfma_f32_16x16x32_bf16(a, b, c, 0, 0, 0);
}

// ---------------- prep: x NCHW fp32 -> NHWC bf16, fused global-avg-pool ----------------
__global__ __launch_bounds__(256) void xT_kernel(const float* __restrict__ x,
                                                 bf16* __restrict__ xT,
                                                 float* __restrict__ pooled) {
  __shared__ float tile[64][65];
  const int p0 = blockIdx.x * 64, c0 = blockIdx.y * 64, b = blockIdx.z;
  const int t = threadIdx.x;
#pragma unroll
  for (int j = 0; j < 16; ++j) {
    int idx = t + j * 256;
    int cl = idx >> 6, pl = idx & 63;
    tile[cl][pl] = x[(size_t)(b * C_ + c0 + cl) * P_ + p0 + pl];
  }
  __syncthreads();
#pragma unroll
  for (int j = 0; j < 16; ++j) {
    int idx = t + j * 256;
    int pl = idx >> 6, cl = idx & 63;
    xT[(size_t)(b * P_ + p0 + pl) * C_ + c0 + cl] = __float2bfloat16(tile[cl][pl]);
  }
  if (t < 64) {
    float s = 0.f;
#pragma unroll 8
    for (int pl = 0; pl < 64; ++pl) s += tile[t][pl];
    atomicAdd(&pooled[b * C_ + c0 + t], s * (1.0f / P_));
  }
}

// ---------------- prep: w1 [E][HID][C][3][3] -> [E][9][HID][C] bf16, BN1 scale folded ----
__global__ __launch_bounds__(256) void w1cvt_kernel(const float* __restrict__ w1,
                                                    const float* __restrict__ bn1_scale,
                                                    bf16* __restrict__ w1b) {
  const int eh = blockIdx.x;           // e*HID + hid
  const int e = eh >> 9, hid = eh & 511;
  __shared__ float buf[2304];
  const float* src = w1 + (size_t)eh * 2304;
  const int t = threadIdx.x;
  for (int i = t; i < 2304; i += 256) buf[i] = src[i];
  __syncthreads();
  const float inv = bn1_scale[eh] * (1.0f / sqrtf(1.0f + EPS_));
  for (int i = t; i < 2304; i += 256) {
    int rs = i >> 8, c = i & 255;
    w1b[((size_t)(e * 9 + rs) * HID_ + hid) * C_ + c] = __float2bfloat16(buf[c * 9 + rs] * inv);
  }
}

// ---------------- prep: w2 -> bf16 with BN2 scale folded ----------------
__global__ __launch_bounds__(256) void w2cvt_kernel(const float* __restrict__ w2,
                                                    const float* __restrict__ bn2_scale,
                                                    bf16* __restrict__ w2b) {
  const int i = blockIdx.x * 256 + threadIdx.x;   // E*O*HID = 1048576
  const int eo = i >> 9;
  w2b[i] = __float2bfloat16(w2[i] * (bn2_scale[eo] * (1.0f / sqrtf(1.0f + EPS_))));
}

// ---------------- prep: shared_w -> bf16 with BN scale folded ----------------
__global__ __launch_bounds__(256) void wshcvt_kernel(const float* __restrict__ wsh,
                                                     const float* __restrict__ sscale,
                                                     bf16* __restrict__ wshb) {
  const int i = blockIdx.x * 256 + threadIdx.x;   // O*C = 65536
  wshb[i] = __float2bfloat16(wsh[i] * (sscale[i >> 8] * (1.0f / sqrtf(1.0f + EPS_))));
}

// ---------------- router: logits/softmax/top2 + gated bias sums ----------------
__global__ __launch_bounds__(256) void router_kernel(const float* __restrict__ pooled,
                                                     const float* __restrict__ rw,
                                                     const float* __restrict__ rb,
                                                     const float* __restrict__ bn2_bias,
                                                     int* __restrict__ ridx,
                                                     float* __restrict__ rwt,
                                                     float* __restrict__ bsum) {
  __shared__ float lp[B_ * C_];
  __shared__ float llog[B_ * E_];
  __shared__ int lidx[B_ * 2];
  __shared__ float lw[B_ * 2];
  const int t = threadIdx.x;
  for (int i = t; i < B_ * C_; i += 256) lp[i] = pooled[i];
  __syncthreads();
  if (t < B_ * E_) {
    int b = t >> 3, e = t & 7;
    float s = rb[e];
    for (int c = 0; c < C_; ++c) s += lp[b * C_ + c] * rw[e * C_ + c];
    llog[t] = s;
  }
  __syncthreads();
  if (t < B_) {
    float pr[E_];
    float m = -1e30f;
    for (int e = 0; e < E_; ++e) { pr[e] = llog[t * E_ + e]; m = fmaxf(m, pr[e]); }
    float s = 0.f;
    for (int e = 0; e < E_; ++e) { pr[e] = __expf(pr[e] - m); s += pr[e]; }
    const float is = 1.f / s;
    for (int e = 0; e < E_; ++e) pr[e] *= is;
    int i0 = 0; float v0 = pr[0];
    for (int e = 1; e < E_; ++e) if (pr[e] > v0) { v0 = pr[e]; i0 = e; }
    int i1 = -1; float v1 = -1.f;
    for (int e = 0; e < E_; ++e) if (e != i0 && pr[e] > v1) { v1 = pr[e]; i1 = e; }
    const float wsum = 1.f / (v0 + v1);
    ridx[t * 2] = i0; ridx[t * 2 + 1] = i1;
    rwt[t * 2] = v0 * wsum; rwt[t * 2 + 1] = v1 * wsum;
    lidx[t * 2] = i0; lidx[t * 2 + 1] = i1;
    lw[t * 2] = v0 * wsum; lw[t * 2 + 1] = v1 * wsum;
  }
  __syncthreads();
  for (int i = t; i < B_ * O_; i += 256) {
    int b = i >> 8, o = i & 255;
    bsum[i] = lw[b * 2] * bn2_bias[lidx[b * 2] * O_ + o]
            + lw[b * 2 + 1] * bn2_bias[lidx[b * 2 + 1] * O_ + o];
  }
}

// ======== 8-phase 256x256x64 template machinery (shared by conv1/combine) ========
// LDS: 8 half-regions of 8192 bf16 (16 KB): region(d, op, half) = (d*4 + op*2 + half).
// A-half = 128 M-rows x 64 K; B-half = 128 N-rows x 64 K. Swizzle: 16B-slot ^= row&7.
// 8 waves as 2M x 4N; wave tile 128 x 64. Per phase: 16 MFMA (mi-half h, k-slice ks).
// Region-death schedule (iter i, k0=2i, k1=2i+1): stages ph0:B0[k1] ph1:A1[k1]
// ph2:B1[k1] ph3:A0[k2] ph4:B0[k2] ph5:A1[k2] ph6:B1[k2] ph7:A0[k3];
// each target region's last reader finished one barrier earlier (proof in journal).
// vmcnt(2) at ph3 (k1 landed) and ph7 (k2 landed); never 0 until the final iter.

#define BARX() do { asm volatile("" ::: "memory"); __builtin_amdgcn_s_barrier(); \
                    asm volatile("" ::: "memory"); } while (0)

#define LOADA(D, H, KS) do { \
  const bf16* p_ = lds + ((D)*4 + wm) * 8192 + (H) * 4096 + arow + sw##KS; \
  af[0] = *(const bf16x8*)(p_); \
  af[1] = *(const bf16x8*)(p_ + 1024); \
  af[2] = *(const bf16x8*)(p_ + 2048); \
  af[3] = *(const bf16x8*)(p_ + 3072); \
} while (0)

#define LOADB(D, KS) do { \
  const bf16* p_ = lds + ((D)*4 + 2 + bhalf) * 8192 + brow + sw##KS; \
  bq[0] = *(const bf16x8*)(p_); \
  bq[1] = *(const bf16x8*)(p_ + 1024); \
  bq[2] = *(const bf16x8*)(p_ + 2048); \
  bq[3] = *(const bf16x8*)(p_ + 3072); \
} while (0)

#define MM(BB) do { \
  __builtin_amdgcn_s_setprio(1); \
  acc[(BB)+0][0]=mfma16(af[0],bq[0],acc[(BB)+0][0]); acc[(BB)+0][1]=mfma16(af[0],bq[1],acc[(BB)+0][1]); \
  acc[(BB)+0][2]=mfma16(af[0],bq[2],acc[(BB)+0][2]); acc[(BB)+0][3]=mfma16(af[0],bq[3],acc[(BB)+0][3]); \
  acc[(BB)+1][0]=mfma16(af[1],bq[0],acc[(BB)+1][0]); acc[(BB)+1][1]=mfma16(af[1],bq[1],acc[(BB)+1][1]); \
  acc[(BB)+1][2]=mfma16(af[1],bq[2],acc[(BB)+1][2]); acc[(BB)+1][3]=mfma16(af[1],bq[3],acc[(BB)+1][3]); \
  acc[(BB)+2][0]=mfma16(af[2],bq[0],acc[(BB)+2][0]); acc[(BB)+2][1]=mfma16(af[2],bq[1],acc[(BB)+2][1]); \
  acc[(BB)+2][2]=mfma16(af[2],bq[2],acc[(BB)+2][2]); acc[(BB)+2][3]=mfma16(af[2],bq[3],acc[(BB)+2][3]); \
  acc[(BB)+3][0]=mfma16(af[3],bq[0],acc[(BB)+3][0]); acc[(BB)+3][1]=mfma16(af[3],bq[1],acc[(BB)+3][1]); \
  acc[(BB)+3][2]=mfma16(af[3],bq[2],acc[(BB)+3][2]); acc[(BB)+3][3]=mfma16(af[3],bq[3],acc[(BB)+3][3]); \
  __builtin_amdgcn_s_setprio(0); \
} while (0)

// ---------------- conv3x3 C->HID per routed (b,slot), implicit GEMM, 8-phase ----------------
__global__ __launch_bounds__(512, 2) void conv1_kernel(
    const bf16* __restrict__ xT, const bf16* __restrict__ w1b,
    const float* __restrict__ bn1_bias, const int* __restrict__ ridx,
    const float* __restrict__ rwt, const bf16* __restrict__ zp,
    bf16* __restrict__ h) {
  __shared__ __align__(16) bf16 lds[65536];     // 128 KB
  const int t = threadIdx.x;
  // grid = 832 = 8 XCD * (4 bs * 26 tiles)
  const int bid = blockIdx.x;
  const int xcd = bid & 7, j = bid >> 3;
  const int bs = xcd * 4 + j / 26;
  const int j2 = j % 26;
  const int mt = j2 % 13, nt = j2 / 13;
  const int p0 = mt * 256, h0 = nt * 256;
  const int b = bs >> 1;
  const int e = ridx[bs];
  const float wk = rwt[bs];

  const int lane = t & 63, wv = t >> 6;
  const int wm = wv >> 2, wn = wv & 3;          // 2M x 4N waves
  const int r16 = lane & 15, q = lane >> 4;
  const int bhalf = wn >> 1;
  const int arow = r16 * 64;
  const int brow = (wn & 1) * 4096 + arow;
  const int sw0 = ((q) ^ (r16 & 7)) * 8;
  const int sw1 = ((4 + q) ^ (r16 & 7)) * 8;

  // staging geometry
  const int srow = t >> 3;                      // 0..63
  const int cho = ((t & 7) ^ (srow & 7)) * 8;   // inverse-swizzled source slot
  int pA[4], yA[4], xA[4];
#pragma unroll
  for (int r = 0; r < 4; ++r) {
    pA[r] = p0 + r * 64 + srow;
    yA[r] = pA[r] / 56;
    xA[r] = pA[r] - yA[r] * 56;
  }
  const bf16* xb = xT + (size_t)b * P_ * C_ + cho;
  const bf16* wb = w1b + ((size_t)(e * 9) * HID_ + h0 + srow) * C_ + cho;
  bf16* lt = lds + t * 8;

#define STAGEA(HALF, KT) do { \
  const int tap_ = (KT) >> 2, ck_ = ((KT) & 3) * 64; \
  const int dr_ = ((tap_ * 11) >> 5) - 1; \
  const int dc_ = tap_ - (dr_ + 1) * 3 - 1; \
  const int off_ = dr_ * 56 + dc_; \
  bf16* d_ = lt + (((KT)&1)*4 + (HALF)) * 8192; \
  { const bool v_ = (pA[(HALF)*2] < P_) & ((unsigned)(yA[(HALF)*2]+dr_) < 56u) & ((unsigned)(xA[(HALF)*2]+dc_) < 56u); \
    gl2lds16(v_ ? xb + (size_t)(pA[(HALF)*2]+off_)*C_ + ck_ : zp, d_); } \
  { const bool v_ = (pA[(HALF)*2+1] < P_) & ((unsigned)(yA[(HALF)*2+1]+dr_) < 56u) & ((unsigned)(xA[(HALF)*2+1]+dc_) < 56u); \
    gl2lds16(v_ ? xb + (size_t)(pA[(HALF)*2+1]+off_)*C_ + ck_ : zp, d_ + 4096); } \
} while (0)

#define STAGEB(HALF, KT) do { \
  const int tap_ = (KT) >> 2, ck_ = ((KT) & 3) * 64; \
  bf16* d_ = lt + (((KT)&1)*4 + 2 + (HALF)) * 8192; \
  const bf16* s_ = wb + ((size_t)tap_ * HID_ + (HALF)*128) * C_ + ck_; \
  gl2lds16(s_, d_); \
  gl2lds16(s_ + (size_t)64 * C_, d_ + 4096); \
} while (0)

  f32x4 acc[8][4] = {};
  bf16x8 af[4], bq[4];

  // prologue: k0 fully, A0 of k1
  STAGEA(0, 0); STAGEB(0, 0); STAGEA(1, 0); STAGEB(1, 0); STAGEA(0, 1);
  asm volatile("s_waitcnt vmcnt(2)" ::: "memory");
  BARX();

  for (int it = 0; it < 18; ++it) {
    const int k1 = 2 * it + 1, k2 = 2 * it + 2, k3 = 2 * it + 3;
    const bool s2 = (k2 < 36), s3 = (k3 < 36);
    // ph0: d0 h0 ks0 | stage B0<-k1
    LOADA(0, 0, 0); LOADB(0, 0); STAGEB(0, k1); BARX(); MM(0); BARX();
    // ph1: d0 h1 ks0 | stage A1<-k1
    LOADA(0, 1, 0); STAGEA(1, k1); BARX(); MM(4); BARX();
    // ph2: d0 h0 ks1 | stage B1<-k1
    LOADA(0, 0, 1); LOADB(0, 1); STAGEB(1, k1); BARX(); MM(0); BARX();
    // ph3: d0 h1 ks1 | stage A0<-k2 | wait: k1 landed
    LOADA(0, 1, 1); if (s2) STAGEA(0, k2); BARX(); MM(4);
    if (s2) asm volatile("s_waitcnt vmcnt(2)" ::: "memory");
    else    asm volatile("s_waitcnt vmcnt(0)" ::: "memory");
    BARX();
    // ph4: d1 h0 ks0 | stage B0<-k2
    LOADA(1, 0, 0); LOADB(1, 0); if (s2) STAGEB(0, k2); BARX(); MM(0); BARX();
    // ph5: d1 h1 ks0 | stage A1<-k2
    LOADA(1, 1, 0); if (s2) STAGEA(1, k2); BARX(); MM(4); BARX();
    // ph6: d1 h0 ks1 | stage B1<-k2
    LOADA(1, 0, 1); LOADB(1, 1); if (s2) STAGEB(1, k2); BARX(); MM(0); BARX();
    // ph7: d1 h1 ks1 | stage A0<-k3 | wait: k2 landed
    LOADA(1, 1, 1); if (s3) STAGEA(0, k3); BARX(); MM(4);
    if (s3) asm volatile("s_waitcnt vmcnt(2)" ::: "memory");
    else    asm volatile("s_waitcnt vmcnt(0)" ::: "memory");
    BARX();
  }
#undef STAGEA
#undef STAGEB

  // epilogue: h[bs][p][hid] = wk * silu(acc + bn1_bias)
  const int rowq = q * 4;
  float bias[4];
#pragma unroll
  for (int ni = 0; ni < 4; ++ni)
    bias[ni] = bn1_bias[e * HID_ + h0 + wn * 64 + ni * 16 + r16];
#pragma unroll
  for (int mi = 0; mi < 8; ++mi) {
#pragma unroll
    for (int i = 0; i < 4; ++i) {
      const int p = p0 + wm * 128 + mi * 16 + rowq + i;
      if (p < P_) {
        const size_t base = ((size_t)bs * P_ + p) * HID_;
#pragma unroll
        for (int ni = 0; ni < 4; ++ni) {
          const int hid = h0 + wn * 64 + ni * 16 + r16;
          float v = acc[mi][ni][i] + bias[ni];
          v = v / (1.f + __expf(-v));
          h[base + hid] = __float2bfloat16(wk * v);
        }
      }
    }
  }
}

// ---------------- combine: shared 1x1 (SiLU at iter boundary) + both experts + residual ----
// BM=256 (all o), BN=256 px (13 tiles), BK=64. NK=20: shared 0-3, e0 4-11, e1 12-19.
__global__ __launch_bounds__(512, 2) void combine_kernel(
    const bf16* __restrict__ xT, const bf16* __restrict__ h,
    const bf16* __restrict__ wshb, const bf16* __restrict__ w2b,
    const float* __restrict__ sbias, const float* __restrict__ bsum,
    const int* __restrict__ ridx, const float* __restrict__ x,
    const bf16* __restrict__ zp, float* __restrict__ out) {
  __shared__ __align__(16) bf16 lds[65536];
  const int t = threadIdx.x;
  // grid = 208 = 8 XCD * (2 b * 13 px-tiles)
  const int bid = blockIdx.x;
  const int xcd = bid & 7, j = bid >> 3;
  const int b = xcd * 2 + j / 13;
  const int pt = j % 13;
  const int p0 = pt * 256;
  const int e0 = ridx[b * 2], e1 = ridx[b * 2 + 1];

  const int lane = t & 63, wv = t >> 6;
  const int wm = wv >> 2, wn = wv & 3;
  const int r16 = lane & 15, q = lane >> 4;
  const int bhalf = wn >> 1;
  const int arow = r16 * 64;
  const int brow = (wn & 1) * 4096 + arow;
  const int sw0 = ((q) ^ (r16 & 7)) * 8;
  const int sw1 = ((4 + q) ^ (r16 & 7)) * 8;

  const int srow = t >> 3;
  const int cho = ((t & 7) ^ (srow & 7)) * 8;
  int pB[4];
#pragma unroll
  for (int r = 0; r < 4; ++r) pB[r] = p0 + r * 64 + srow;
  const bf16* wshp = wshb + (size_t)srow * C_ + cho;
  const bf16* w2p0 = w2b + ((size_t)(e0 * O_) + srow) * HID_ + cho;
  const bf16* w2p1 = w2b + ((size_t)(e1 * O_) + srow) * HID_ + cho;
  const bf16* xp = xT + (size_t)b * P_ * C_ + cho;
  const bf16* hp0 = h + (size_t)(b * 2) * P_ * HID_ + cho;
  const bf16* hp1 = h + (size_t)(b * 2 + 1) * P_ * HID_ + cho;
  bf16* lt = lds + t * 8;

#define CSTAGEA(HALF, KT) do { \
  bf16* d_ = lt + (((KT)&1)*4 + (HALF)) * 8192; \
  const bf16* s0_; \
  size_t rstep_; \
  if ((KT) < 4)       { s0_ = wshp + (size_t)((HALF)*128)*C_   + (KT)*64;      rstep_ = (size_t)64*C_; } \
  else if ((KT) < 12) { s0_ = w2p0 + (size_t)((HALF)*128)*HID_ + ((KT)-4)*64;  rstep_ = (size_t)64*HID_; } \
  else                { s0_ = w2p1 + (size_t)((HALF)*128)*HID_ + ((KT)-12)*64; rstep_ = (size_t)64*HID_; } \
  gl2lds16(s0_, d_); \
  gl2lds16(s0_ + rstep_, d_ + 4096); \
} while (0)

#define CSTAGEB(HALF, KT) do { \
  bf16* d_ = lt + (((KT)&1)*4 + 2 + (HALF)) * 8192; \
  if ((KT) < 4) { const int ck_ = (KT)*64; \
    gl2lds16(pB[(HALF)*2] < P_ ? xp + (size_t)pB[(HALF)*2]*C_ + ck_ : zp, d_); \
    gl2lds16(pB[(HALF)*2+1] < P_ ? xp + (size_t)pB[(HALF)*2+1]*C_ + ck_ : zp, d_ + 4096); \
  } else { \
    const bf16* hb_ = (KT) < 12 ? hp0 : hp1; \
    const int ck_ = ((KT) < 12 ? (KT)-4 : (KT)-12) * 64; \
    gl2lds16(pB[(HALF)*2] < P_ ? hb_ + (size_t)pB[(HALF)*2]*HID_ + ck_ : zp, d_); \
    gl2lds16(pB[(HALF)*2+1] < P_ ? hb_ + (size_t)pB[(HALF)*2+1]*HID_ + ck_ : zp, d_ + 4096); \
  } \
} while (0)

  const int rowq = q * 4;
  f32x4 acc[8][4] = {};
  bf16x8 af[4], bq[4];

  CSTAGEA(0, 0); CSTAGEB(0, 0); CSTAGEA(1, 0); CSTAGEB(1, 0); CSTAGEA(0, 1);
  asm volatile("s_waitcnt vmcnt(2)" ::: "memory");
  BARX();

  for (int it = 0; it < 10; ++it) {
    const int k1 = 2 * it + 1, k2 = 2 * it + 2, k3 = 2 * it + 3;
    const bool s2 = (k2 < 20), s3 = (k3 < 20);
    LOADA(0, 0, 0); LOADB(0, 0); CSTAGEB(0, k1); BARX(); MM(0); BARX();
    LOADA(0, 1, 0); CSTAGEA(1, k1); BARX(); MM(4); BARX();
    LOADA(0, 0, 1); LOADB(0, 1); CSTAGEB(1, k1); BARX(); MM(0); BARX();
    LOADA(0, 1, 1); if (s2) CSTAGEA(0, k2); BARX(); MM(4);
    if (s2) asm volatile("s_waitcnt vmcnt(2)" ::: "memory");
    else    asm volatile("s_waitcnt vmcnt(0)" ::: "memory");
    BARX();
    LOADA(1, 0, 0); LOADB(1, 0); if (s2) CSTAGEB(0, k2); BARX(); MM(0); BARX();
    LOADA(1, 1, 0); if (s2) CSTAGEA(1, k2); BARX(); MM(4); BARX();
    LOADA(1, 0, 1); LOADB(1, 1); if (s2) CSTAGEB(1, k2); BARX(); MM(0); BARX();
    LOADA(1, 1, 1); if (s3) CSTAGEA(0, k3); BARX(); MM(4);
    if (s3) asm volatile("s_waitcnt vmcnt(2)" ::: "memory");
    else    asm volatile("s_waitcnt vmcnt(0)" ::: "memory");
    BARX();
    if (it == 1) {   // shared expert (kt 0-3) complete: acc = silu(acc + sbias)
#pragma unroll
      for (int mi = 0; mi < 8; ++mi)
#pragma unroll
        for (int i = 0; i < 4; ++i) {
          const float bias_ = sbias[wm * 128 + mi * 16 + rowq + i];
#pragma unroll
          for (int ni = 0; ni < 4; ++ni) {
            float v = acc[mi][ni][i] + bias_;
            acc[mi][ni][i] = v / (1.f + __expf(-v));
          }
        }
    }
  }
#undef CSTAGEA
#undef CSTAGEB

#pragma unroll
  for (int mi = 0; mi < 8; ++mi) {
#pragma unroll
    for (int i = 0; i < 4; ++i) {
      const int o = wm * 128 + mi * 16 + rowq + i;
      const float bb = bsum[b * O_ + o];
      const size_t orow = (size_t)(b * O_ + o) * P_;
#pragma unroll
      for (int ni = 0; ni < 4; ++ni) {
        const int p = p0 + wn * 64 + ni * 16 + r16;
        if (p < P_) out[orow + p] = acc[mi][ni][i] + bb + x[orow + p];
      }
    }
  }
}

// ---------------- workspace layout ----------------
constexpr size_t SZ_XT = (size_t)B_ * P_ * C_ * 2;
constexpr size_t SZ_W1B = (size_t)E_ * 9 * HID_ * C_ * 2;
constexpr size_t SZ_W2B = (size_t)E_ * O_ * HID_ * 2;
constexpr size_t SZ_WSHB = (size_t)O_ * C_ * 2;
constexpr size_t SZ_POOL = (size_t)B_ * C_ * 4;
constexpr size_t SZ_BSUM = (size_t)B_ * O_ * 4;

constexpr size_t OFF_XT = 0;
constexpr size_t OFF_W1B = OFF_XT + SZ_XT;
constexpr size_t OFF_W2B = OFF_W1B + SZ_W1B;
constexpr size_t OFF_WSHB = OFF_W2B + SZ_W2B;
constexpr size_t OFF_POOL = OFF_WSHB + SZ_WSHB;
constexpr size_t OFF_RIDX = OFF_POOL + SZ_POOL;   // 128 B
constexpr size_t OFF_RWT = OFF_RIDX + 128;        // 128 B
constexpr size_t OFF_BSUM = OFF_RWT + 128;
constexpr size_t OFF_ZERO = OFF_BSUM + SZ_BSUM;   // 1024 B zero page
constexpr size_t OFF_H = OFF_ZERO + 1024;

extern "C" void kernel_launch(void* const* d_in, const int* in_sizes, int n_in,
                              void* d_out, int out_size, void* d_ws, size_t ws_size,
                              hipStream_t stream) {
  const float* x = (const float*)d_in[0];
  const float* router_w = (const float*)d_in[1];
  const float* router_b = (const float*)d_in[2];
  const float* shared_w = (const float*)d_in[3];
  const float* shared_scale = (const float*)d_in[4];
  const float* shared_bias = (const float*)d_in[5];
  const float* w1 = (const float*)d_in[6];
  const float* bn1_scale = (const float*)d_in[7];
  const float* bn1_bias = (const float*)d_in[8];
  const float* w2 = (const float*)d_in[9];
  const float* bn2_scale = (const float*)d_in[10];
  const float* bn2_bias = (const float*)d_in[11];
  float* out = (float*)d_out;
  char* ws = (char*)d_ws;

  bf16* xT = (bf16*)(ws + OFF_XT);
  bf16* w1b = (bf16*)(ws + OFF_W1B);
  bf16* w2b = (bf16*)(ws + OFF_W2B);
  bf16* wshb = (bf16*)(ws + OFF_WSHB);
  float* pooled = (float*)(ws + OFF_POOL);
  int* ridx = (int*)(ws + OFF_RIDX);
  float* rwt = (float*)(ws + OFF_RWT);
  float* bsum = (float*)(ws + OFF_BSUM);
  bf16* zp = (bf16*)(ws + OFF_ZERO);
  bf16* h = (bf16*)(ws + OFF_H);

  hipMemsetAsync(ws + OFF_POOL, 0, SZ_POOL, stream);
  hipMemsetAsync(ws + OFF_ZERO, 0, 1024, stream);

  xT_kernel<<<dim3(49, 4, 16), 256, 0, stream>>>(x, xT, pooled);
  w1cvt_kernel<<<E_ * HID_, 256, 0, stream>>>(w1, bn1_scale, w1b);
  w2cvt_kernel<<<(E_ * O_ * HID_) / 256, 256, 0, stream>>>(w2, bn2_scale, w2b);
  wshcvt_kernel<<<(O_ * C_) / 256, 256, 0, stream>>>(shared_w, shared_scale, wshb);
  router_kernel<<<1, 256, 0, stream>>>(pooled, router_w, router_b, bn2_bias, ridx, rwt, bsum);
  conv1_kernel<<<832, 512, 0, stream>>>(xT, w1b, bn1_bias, ridx, rwt, zp, h);
  combine_kernel<<<208, 512, 0, stream>>>(xT, h, wshb, w2b, shared_bias, bsum, ridx, x, zp, out);
}

// Round 6
// 553.486 us; speedup vs baseline: 1.2205x; 1.0110x over previous
//
#include <hip/hip_runtime.h>
#include <hip/hip_bf16.h>

#define B_ 16
#define C_ 256
#define O_ 256
#define P_ 3136
#define E_ 8
#define HID_ 512
#define EPS_ 1e-5f

typedef __attribute__((ext_vector_type(8))) short bf16x8;
typedef __attribute__((ext_vector_type(4))) float f32x4;
typedef __hip_bfloat16 bf16;

__device__ __forceinline__ void gl2lds16(const bf16* g, bf16* l) {
  __builtin_amdgcn_global_load_lds((const __attribute__((address_space(1))) void*)g,
                                   (__attribute__((address_space(3))) void*)l,
                                   16, 0, 0);
}

__device__ __forceinline__ f32x4 mfma16(bf16x8 a, bf16x8 b, f32x4 c) {
  return __builtin_amdgcn_mfma_f32_16x16x32_bf16(a, b, c, 0, 0, 0);
}

// ---------------- prep: x NCHW fp32 -> NHWC bf16, fused global-avg-pool ----------------
__global__ __launch_bounds__(256) void xT_kernel(const float* __restrict__ x,
                                                 bf16* __restrict__ xT,
                                                 float* __restrict__ pooled) {
  __shared__ float tile[64][65];
  const int p0 = blockIdx.x * 64, c0 = blockIdx.y * 64, b = blockIdx.z;
  const int t = threadIdx.x;
#pragma unroll
  for (int j = 0; j < 16; ++j) {
    int idx = t + j * 256;
    int cl = idx >> 6, pl = idx & 63;
    tile[cl][pl] = x[(size_t)(b * C_ + c0 + cl) * P_ + p0 + pl];
  }
  __syncthreads();
#pragma unroll
  for (int j = 0; j < 16; ++j) {
    int idx = t + j * 256;
    int pl = idx >> 6, cl = idx & 63;
    xT[(size_t)(b * P_ + p0 + pl) * C_ + c0 + cl] = __float2bfloat16(tile[cl][pl]);
  }
  if (t < 64) {
    float s = 0.f;
#pragma unroll 8
    for (int pl = 0; pl < 64; ++pl) s += tile[t][pl];
    atomicAdd(&pooled[b * C_ + c0 + t], s * (1.0f / P_));
  }
}

// ---------------- prep: w1 [E][HID][C][3][3] -> [E][9][HID][C] bf16, BN1 scale folded ----
__global__ __launch_bounds__(256) void w1cvt_kernel(const float* __restrict__ w1,
                                                    const float* __restrict__ bn1_scale,
                                                    bf16* __restrict__ w1b) {
  const int eh = blockIdx.x;           // e*HID + hid
  const int e = eh >> 9, hid = eh & 511;
  __shared__ float buf[2304];
  const float* src = w1 + (size_t)eh * 2304;
  const int t = threadIdx.x;
  for (int i = t; i < 2304; i += 256) buf[i] = src[i];
  __syncthreads();
  const float inv = bn1_scale[eh] * (1.0f / sqrtf(1.0f + EPS_));
  for (int i = t; i < 2304; i += 256) {
    int rs = i >> 8, c = i & 255;
    w1b[((size_t)(e * 9 + rs) * HID_ + hid) * C_ + c] = __float2bfloat16(buf[c * 9 + rs] * inv);
  }
}

// ---------------- prep: w2 -> bf16 with BN2 scale folded ----------------
__global__ __launch_bounds__(256) void w2cvt_kernel(const float* __restrict__ w2,
                                                    const float* __restrict__ bn2_scale,
                                                    bf16* __restrict__ w2b) {
  const int i = blockIdx.x * 256 + threadIdx.x;   // E*O*HID = 1048576
  const int eo = i >> 9;
  w2b[i] = __float2bfloat16(w2[i] * (bn2_scale[eo] * (1.0f / sqrtf(1.0f + EPS_))));
}

// ---------------- prep: shared_w -> bf16 with BN scale folded ----------------
__global__ __launch_bounds__(256) void wshcvt_kernel(const float* __restrict__ wsh,
                                                     const float* __restrict__ sscale,
                                                     bf16* __restrict__ wshb) {
  const int i = blockIdx.x * 256 + threadIdx.x;   // O*C = 65536
  wshb[i] = __float2bfloat16(wsh[i] * (sscale[i >> 8] * (1.0f / sqrtf(1.0f + EPS_))));
}

// ---------------- router: logits/softmax/top2 + gated bias sums ----------------
__global__ __launch_bounds__(256) void router_kernel(const float* __restrict__ pooled,
                                                     const float* __restrict__ rw,
                                                     const float* __restrict__ rb,
                                                     const float* __restrict__ bn2_bias,
                                                     int* __restrict__ ridx,
                                                     float* __restrict__ rwt,
                                                     float* __restrict__ bsum) {
  __shared__ float lp[B_ * C_];
  __shared__ float llog[B_ * E_];
  __shared__ int lidx[B_ * 2];
  __shared__ float lw[B_ * 2];
  const int t = threadIdx.x;
  for (int i = t; i < B_ * C_; i += 256) lp[i] = pooled[i];
  __syncthreads();
  if (t < B_ * E_) {
    int b = t >> 3, e = t & 7;
    float s = rb[e];
    for (int c = 0; c < C_; ++c) s += lp[b * C_ + c] * rw[e * C_ + c];
    llog[t] = s;
  }
  __syncthreads();
  if (t < B_) {
    float pr[E_];
    float m = -1e30f;
    for (int e = 0; e < E_; ++e) { pr[e] = llog[t * E_ + e]; m = fmaxf(m, pr[e]); }
    float s = 0.f;
    for (int e = 0; e < E_; ++e) { pr[e] = __expf(pr[e] - m); s += pr[e]; }
    const float is = 1.f / s;
    for (int e = 0; e < E_; ++e) pr[e] *= is;
    int i0 = 0; float v0 = pr[0];
    for (int e = 1; e < E_; ++e) if (pr[e] > v0) { v0 = pr[e]; i0 = e; }
    int i1 = -1; float v1 = -1.f;
    for (int e = 0; e < E_; ++e) if (e != i0 && pr[e] > v1) { v1 = pr[e]; i1 = e; }
    const float wsum = 1.f / (v0 + v1);
    ridx[t * 2] = i0; ridx[t * 2 + 1] = i1;
    rwt[t * 2] = v0 * wsum; rwt[t * 2 + 1] = v1 * wsum;
    lidx[t * 2] = i0; lidx[t * 2 + 1] = i1;
    lw[t * 2] = v0 * wsum; lw[t * 2 + 1] = v1 * wsum;
  }
  __syncthreads();
  for (int i = t; i < B_ * O_; i += 256) {
    int b = i >> 8, o = i & 255;
    bsum[i] = lw[b * 2] * bn2_bias[lidx[b * 2] * O_ + o]
            + lw[b * 2 + 1] * bn2_bias[lidx[b * 2 + 1] * O_ + o];
  }
}

// ======== 8-phase 256x256x64 template machinery (shared by conv1/combine) ========
// LDS: 8 half-regions of 8192 bf16 (16 KB): region(d, op, half) = (d*4 + op*2 + half).
// Swizzle: 16B-slot ^= row&7. 8 waves as 2M x 4N; wave tile 128 x 64.
// Fragment loads are INLINE-ASM ds_read_b128 (invisible to the waitcnt pass, so the
// counted vmcnt(2) pipeline is not defeated by compiler-inserted vmcnt(0) drains);
// per rule #18 each MFMA cluster is fenced by s_waitcnt lgkmcnt(0) + sched_barrier(0).
// ds address = low 32 bits of the flat LDS pointer (aperture places LDS byte offset
// verbatim in the low word on gfx9+).
// Region-death schedule (iter i, k0=2i, k1=2i+1): stages ph0:B0[k1] ph1:A1[k1]
// ph2:B1[k1] ph3:A0[k2] ph4:B0[k2] ph5:A1[k2] ph6:B1[k2] ph7:A0[k3];
// vmcnt(2) at ph3 (k1 landed) and ph7 (k2 landed); never 0 until the final iter.

#define BARX() do { asm volatile("" ::: "memory"); __builtin_amdgcn_s_barrier(); \
                    asm volatile("" ::: "memory"); } while (0)

#define WAITK() do { asm volatile("s_waitcnt lgkmcnt(0)" ::: "memory"); \
                     __builtin_amdgcn_sched_barrier(0); } while (0)

#define DSR0(dst, a) asm volatile("ds_read_b128 %0, %1"             : "=v"(dst) : "v"(a))
#define DSR1(dst, a) asm volatile("ds_read_b128 %0, %1 offset:2048" : "=v"(dst) : "v"(a))
#define DSR2(dst, a) asm volatile("ds_read_b128 %0, %1 offset:4096" : "=v"(dst) : "v"(a))
#define DSR3(dst, a) asm volatile("ds_read_b128 %0, %1 offset:6144" : "=v"(dst) : "v"(a))

#define LOADA(D, H, KS) do { \
  const unsigned a_ = (unsigned)(uintptr_t)(lds + ((D)*4 + wm) * 8192 + (H) * 4096 + arow + sw##KS); \
  DSR0(af[0], a_); DSR1(af[1], a_); DSR2(af[2], a_); DSR3(af[3], a_); \
} while (0)

#define LOADB(D, KS) do { \
  const unsigned a_ = (unsigned)(uintptr_t)(lds + ((D)*4 + 2 + bhalf) * 8192 + brow + sw##KS); \
  DSR0(bq[0], a_); DSR1(bq[1], a_); DSR2(bq[2], a_); DSR3(bq[3], a_); \
} while (0)

#define MM(BB) do { \
  __builtin_amdgcn_s_setprio(1); \
  acc[(BB)+0][0]=mfma16(af[0],bq[0],acc[(BB)+0][0]); acc[(BB)+0][1]=mfma16(af[0],bq[1],acc[(BB)+0][1]); \
  acc[(BB)+0][2]=mfma16(af[0],bq[2],acc[(BB)+0][2]); acc[(BB)+0][3]=mfma16(af[0],bq[3],acc[(BB)+0][3]); \
  acc[(BB)+1][0]=mfma16(af[1],bq[0],acc[(BB)+1][0]); acc[(BB)+1][1]=mfma16(af[1],bq[1],acc[(BB)+1][1]); \
  acc[(BB)+1][2]=mfma16(af[1],bq[2],acc[(BB)+1][2]); acc[(BB)+1][3]=mfma16(af[1],bq[3],acc[(BB)+1][3]); \
  acc[(BB)+2][0]=mfma16(af[2],bq[0],acc[(BB)+2][0]); acc[(BB)+2][1]=mfma16(af[2],bq[1],acc[(BB)+2][1]); \
  acc[(BB)+2][2]=mfma16(af[2],bq[2],acc[(BB)+2][2]); acc[(BB)+2][3]=mfma16(af[2],bq[3],acc[(BB)+2][3]); \
  acc[(BB)+3][0]=mfma16(af[3],bq[0],acc[(BB)+3][0]); acc[(BB)+3][1]=mfma16(af[3],bq[1],acc[(BB)+3][1]); \
  acc[(BB)+3][2]=mfma16(af[3],bq[2],acc[(BB)+3][2]); acc[(BB)+3][3]=mfma16(af[3],bq[3],acc[(BB)+3][3]); \
  __builtin_amdgcn_s_setprio(0); \
} while (0)

// ---------------- conv3x3 C->HID per routed (b,slot), implicit GEMM, 8-phase ----------------
__global__ __launch_bounds__(512, 2) void conv1_kernel(
    const bf16* __restrict__ xT, const bf16* __restrict__ w1b,
    const float* __restrict__ bn1_bias, const int* __restrict__ ridx,
    const float* __restrict__ rwt, const bf16* __restrict__ zp,
    bf16* __restrict__ h) {
  __shared__ __align__(16) bf16 lds[65536];     // 128 KB
  const int t = threadIdx.x;
  // grid = 832 = 8 XCD * (4 bs * 26 tiles)
  const int bid = blockIdx.x;
  const int xcd = bid & 7, j = bid >> 3;
  const int bs = xcd * 4 + j / 26;
  const int j2 = j % 26;
  const int mt = j2 % 13, nt = j2 / 13;
  const int p0 = mt * 256, h0 = nt * 256;
  const int b = bs >> 1;
  const int e = ridx[bs];
  const float wk = rwt[bs];

  const int lane = t & 63, wv = t >> 6;
  const int wm = wv >> 2, wn = wv & 3;          // 2M x 4N waves
  const int r16 = lane & 15, q = lane >> 4;
  const int bhalf = wn >> 1;
  const int arow = r16 * 64;
  const int brow = (wn & 1) * 4096 + arow;
  const int sw0 = ((q) ^ (r16 & 7)) * 8;
  const int sw1 = ((4 + q) ^ (r16 & 7)) * 8;

  // staging geometry
  const int srow = t >> 3;                      // 0..63
  const int cho = ((t & 7) ^ (srow & 7)) * 8;   // inverse-swizzled source slot
  int pA[4], yA[4], xA[4];
#pragma unroll
  for (int r = 0; r < 4; ++r) {
    pA[r] = p0 + r * 64 + srow;
    yA[r] = pA[r] / 56;
    xA[r] = pA[r] - yA[r] * 56;
  }
  const bf16* xb = xT + (size_t)b * P_ * C_ + cho;
  const bf16* wb = w1b + ((size_t)(e * 9) * HID_ + h0 + srow) * C_ + cho;
  bf16* lt = lds + t * 8;

#define STAGEA(HALF, KT) do { \
  const int tap_ = (KT) >> 2, ck_ = ((KT) & 3) * 64; \
  const int dr_ = ((tap_ * 11) >> 5) - 1; \
  const int dc_ = tap_ - (dr_ + 1) * 3 - 1; \
  const int off_ = dr_ * 56 + dc_; \
  bf16* d_ = lt + (((KT)&1)*4 + (HALF)) * 8192; \
  { const bool v_ = (pA[(HALF)*2] < P_) & ((unsigned)(yA[(HALF)*2]+dr_) < 56u) & ((unsigned)(xA[(HALF)*2]+dc_) < 56u); \
    gl2lds16(v_ ? xb + (size_t)(pA[(HALF)*2]+off_)*C_ + ck_ : zp, d_); } \
  { const bool v_ = (pA[(HALF)*2+1] < P_) & ((unsigned)(yA[(HALF)*2+1]+dr_) < 56u) & ((unsigned)(xA[(HALF)*2+1]+dc_) < 56u); \
    gl2lds16(v_ ? xb + (size_t)(pA[(HALF)*2+1]+off_)*C_ + ck_ : zp, d_ + 4096); } \
} while (0)

#define STAGEB(HALF, KT) do { \
  const int tap_ = (KT) >> 2, ck_ = ((KT) & 3) * 64; \
  bf16* d_ = lt + (((KT)&1)*4 + 2 + (HALF)) * 8192; \
  const bf16* s_ = wb + ((size_t)tap_ * HID_ + (HALF)*128) * C_ + ck_; \
  gl2lds16(s_, d_); \
  gl2lds16(s_ + (size_t)64 * C_, d_ + 4096); \
} while (0)

  f32x4 acc[8][4] = {};
  bf16x8 af[4], bq[4];

  // prologue: k0 fully, A0 of k1
  STAGEA(0, 0); STAGEB(0, 0); STAGEA(1, 0); STAGEB(1, 0); STAGEA(0, 1);
  asm volatile("s_waitcnt vmcnt(2)" ::: "memory");
  BARX();

  for (int it = 0; it < 18; ++it) {
    const int k1 = 2 * it + 1, k2 = 2 * it + 2, k3 = 2 * it + 3;
    const bool s2 = (k2 < 36), s3 = (k3 < 36);
    // ph0: d0 h0 ks0 | stage B0<-k1
    LOADA(0, 0, 0); LOADB(0, 0); STAGEB(0, k1); BARX(); WAITK(); MM(0); BARX();
    // ph1: d0 h1 ks0 | stage A1<-k1
    LOADA(0, 1, 0); STAGEA(1, k1); BARX(); WAITK(); MM(4); BARX();
    // ph2: d0 h0 ks1 | stage B1<-k1
    LOADA(0, 0, 1); LOADB(0, 1); STAGEB(1, k1); BARX(); WAITK(); MM(0); BARX();
    // ph3: d0 h1 ks1 | stage A0<-k2 | wait: k1 landed
    LOADA(0, 1, 1); if (s2) STAGEA(0, k2); BARX(); WAITK(); MM(4);
    if (s2) asm volatile("s_waitcnt vmcnt(2)" ::: "memory");
    else    asm volatile("s_waitcnt vmcnt(0)" ::: "memory");
    BARX();
    // ph4: d1 h0 ks0 | stage B0<-k2
    LOADA(1, 0, 0); LOADB(1, 0); if (s2) STAGEB(0, k2); BARX(); WAITK(); MM(0); BARX();
    // ph5: d1 h1 ks0 | stage A1<-k2
    LOADA(1, 1, 0); if (s2) STAGEA(1, k2); BARX(); WAITK(); MM(4); BARX();
    // ph6: d1 h0 ks1 | stage B1<-k2
    LOADA(1, 0, 1); LOADB(1, 1); if (s2) STAGEB(1, k2); BARX(); WAITK(); MM(0); BARX();
    // ph7: d1 h1 ks1 | stage A0<-k3 | wait: k2 landed
    LOADA(1, 1, 1); if (s3) STAGEA(0, k3); BARX(); WAITK(); MM(4);
    if (s3) asm volatile("s_waitcnt vmcnt(2)" ::: "memory");
    else    asm volatile("s_waitcnt vmcnt(0)" ::: "memory");
    BARX();
  }
#undef STAGEA
#undef STAGEB

  // epilogue: h[bs][p][hid] = wk * silu(acc + bn1_bias)
  const int rowq = q * 4;
  float bias[4];
#pragma unroll
  for (int ni = 0; ni < 4; ++ni)
    bias[ni] = bn1_bias[e * HID_ + h0 + wn * 64 + ni * 16 + r16];
#pragma unroll
  for (int mi = 0; mi < 8; ++mi) {
#pragma unroll
    for (int i = 0; i < 4; ++i) {
      const int p = p0 + wm * 128 + mi * 16 + rowq + i;
      if (p < P_) {
        const size_t base = ((size_t)bs * P_ + p) * HID_;
#pragma unroll
        for (int ni = 0; ni < 4; ++ni) {
          const int hid = h0 + wn * 64 + ni * 16 + r16;
          float v = acc[mi][ni][i] + bias[ni];
          v = v / (1.f + __expf(-v));
          h[base + hid] = __float2bfloat16(wk * v);
        }
      }
    }
  }
}

// ---------------- combine: shared 1x1 (SiLU at iter boundary) + both experts + residual ----
// BM=256 (all o), BN=256 px (13 tiles), BK=64. NK=20: shared 0-3, e0 4-11, e1 12-19.
__global__ __launch_bounds__(512, 2) void combine_kernel(
    const bf16* __restrict__ xT, const bf16* __restrict__ h,
    const bf16* __restrict__ wshb, const bf16* __restrict__ w2b,
    const float* __restrict__ sbias, const float* __restrict__ bsum,
    const int* __restrict__ ridx, const float* __restrict__ x,
    const bf16* __restrict__ zp, float* __restrict__ out) {
  __shared__ __align__(16) bf16 lds[65536];
  const int t = threadIdx.x;
  // grid = 208 = 8 XCD * (2 b * 13 px-tiles)
  const int bid = blockIdx.x;
  const int xcd = bid & 7, j = bid >> 3;
  const int b = xcd * 2 + j / 13;
  const int pt = j % 13;
  const int p0 = pt * 256;
  const int e0 = ridx[b * 2], e1 = ridx[b * 2 + 1];

  const int lane = t & 63, wv = t >> 6;
  const int wm = wv >> 2, wn = wv & 3;
  const int r16 = lane & 15, q = lane >> 4;
  const int bhalf = wn >> 1;
  const int arow = r16 * 64;
  const int brow = (wn & 1) * 4096 + arow;
  const int sw0 = ((q) ^ (r16 & 7)) * 8;
  const int sw1 = ((4 + q) ^ (r16 & 7)) * 8;

  const int srow = t >> 3;
  const int cho = ((t & 7) ^ (srow & 7)) * 8;
  int pB[4];
#pragma unroll
  for (int r = 0; r < 4; ++r) pB[r] = p0 + r * 64 + srow;
  const bf16* wshp = wshb + (size_t)srow * C_ + cho;
  const bf16* w2p0 = w2b + ((size_t)(e0 * O_) + srow) * HID_ + cho;
  const bf16* w2p1 = w2b + ((size_t)(e1 * O_) + srow) * HID_ + cho;
  const bf16* xp = xT + (size_t)b * P_ * C_ + cho;
  const bf16* hp0 = h + (size_t)(b * 2) * P_ * HID_ + cho;
  const bf16* hp1 = h + (size_t)(b * 2 + 1) * P_ * HID_ + cho;
  bf16* lt = lds + t * 8;

#define CSTAGEA(HALF, KT) do { \
  bf16* d_ = lt + (((KT)&1)*4 + (HALF)) * 8192; \
  const bf16* s0_; \
  size_t rstep_; \
  if ((KT) < 4)       { s0_ = wshp + (size_t)((HALF)*128)*C_   + (KT)*64;      rstep_ = (size_t)64*C_; } \
  else if ((KT) < 12) { s0_ = w2p0 + (size_t)((HALF)*128)*HID_ + ((KT)-4)*64;  rstep_ = (size_t)64*HID_; } \
  else                { s0_ = w2p1 + (size_t)((HALF)*128)*HID_ + ((KT)-12)*64; rstep_ = (size_t)64*HID_; } \
  gl2lds16(s0_, d_); \
  gl2lds16(s0_ + rstep_, d_ + 4096); \
} while (0)

#define CSTAGEB(HALF, KT) do { \
  bf16* d_ = lt + (((KT)&1)*4 + 2 + (HALF)) * 8192; \
  if ((KT) < 4) { const int ck_ = (KT)*64; \
    gl2lds16(pB[(HALF)*2] < P_ ? xp + (size_t)pB[(HALF)*2]*C_ + ck_ : zp, d_); \
    gl2lds16(pB[(HALF)*2+1] < P_ ? xp + (size_t)pB[(HALF)*2+1]*C_ + ck_ : zp, d_ + 4096); \
  } else { \
    const bf16* hb_ = (KT) < 12 ? hp0 : hp1; \
    const int ck_ = ((KT) < 12 ? (KT)-4 : (KT)-12) * 64; \
    gl2lds16(pB[(HALF)*2] < P_ ? hb_ + (size_t)pB[(HALF)*2]*HID_ + ck_ : zp, d_); \
    gl2lds16(pB[(HALF)*2+1] < P_ ? hb_ + (size_t)pB[(HALF)*2+1]*HID_ + ck_ : zp, d_ + 4096); \
  } \
} while (0)

  const int rowq = q * 4;
  f32x4 acc[8][4] = {};
  bf16x8 af[4], bq[4];

  CSTAGEA(0, 0); CSTAGEB(0, 0); CSTAGEA(1, 0); CSTAGEB(1, 0); CSTAGEA(0, 1);
  asm volatile("s_waitcnt vmcnt(2)" ::: "memory");
  BARX();

  for (int it = 0; it < 10; ++it) {
    const int k1 = 2 * it + 1, k2 = 2 * it + 2, k3 = 2 * it + 3;
    const bool s2 = (k2 < 20), s3 = (k3 < 20);
    LOADA(0, 0, 0); LOADB(0, 0); CSTAGEB(0, k1); BARX(); WAITK(); MM(0); BARX();
    LOADA(0, 1, 0); CSTAGEA(1, k1); BARX(); WAITK(); MM(4); BARX();
    LOADA(0, 0, 1); LOADB(0, 1); CSTAGEB(1, k1); BARX(); WAITK(); MM(0); BARX();
    LOADA(0, 1, 1); if (s2) CSTAGEA(0, k2); BARX(); WAITK(); MM(4);
    if (s2) asm volatile("s_waitcnt vmcnt(2)" ::: "memory");
    else    asm volatile("s_waitcnt vmcnt(0)" ::: "memory");
    BARX();
    LOADA(1, 0, 0); LOADB(1, 0); if (s2) CSTAGEB(0, k2); BARX(); WAITK(); MM(0); BARX();
    LOADA(1, 1, 0); if (s2) CSTAGEA(1, k2); BARX(); WAITK(); MM(4); BARX();
    LOADA(1, 0, 1); LOADB(1, 1); if (s2) CSTAGEB(1, k2); BARX(); WAITK(); MM(0); BARX();
    LOADA(1, 1, 1); if (s3) CSTAGEA(0, k3); BARX(); WAITK(); MM(4);
    if (s3) asm volatile("s_waitcnt vmcnt(2)" ::: "memory");
    else    asm volatile("s_waitcnt vmcnt(0)" ::: "memory");
    BARX();
    if (it == 1) {   // shared expert (kt 0-3) complete: acc = silu(acc + sbias)
#pragma unroll
      for (int mi = 0; mi < 8; ++mi)
#pragma unroll
        for (int i = 0; i < 4; ++i) {
          const float bias_ = sbias[wm * 128 + mi * 16 + rowq + i];
#pragma unroll
          for (int ni = 0; ni < 4; ++ni) {
            float v = acc[mi][ni][i] + bias_;
            acc[mi][ni][i] = v / (1.f + __expf(-v));
          }
        }
    }
  }
#undef CSTAGEA
#undef CSTAGEB

#pragma unroll
  for (int mi = 0; mi < 8; ++mi) {
#pragma unroll
    for (int i = 0; i < 4; ++i) {
      const int o = wm * 128 + mi * 16 + rowq + i;
      const float bb = bsum[b * O_ + o];
      const size_t orow = (size_t)(b * O_ + o) * P_;
#pragma unroll
      for (int ni = 0; ni < 4; ++ni) {
        const int p = p0 + wn * 64 + ni * 16 + r16;
        if (p < P_) out[orow + p] = acc[mi][ni][i] + bb + x[orow + p];
      }
    }
  }
}

// ---------------- workspace layout ----------------
constexpr size_t SZ_XT = (size_t)B_ * P_ * C_ * 2;
constexpr size_t SZ_W1B = (size_t)E_ * 9 * HID_ * C_ * 2;
constexpr size_t SZ_W2B = (size_t)E_ * O_ * HID_ * 2;
constexpr size_t SZ_WSHB = (size_t)O_ * C_ * 2;
constexpr size_t SZ_POOL = (size_t)B_ * C_ * 4;
constexpr size_t SZ_BSUM = (size_t)B_ * O_ * 4;

constexpr size_t OFF_XT = 0;
constexpr size_t OFF_W1B = OFF_XT + SZ_XT;
constexpr size_t OFF_W2B = OFF_W1B + SZ_W1B;
constexpr size_t OFF_WSHB = OFF_W2B + SZ_W2B;
constexpr size_t OFF_POOL = OFF_WSHB + SZ_WSHB;
constexpr size_t OFF_RIDX = OFF_POOL + SZ_POOL;   // 128 B
constexpr size_t OFF_RWT = OFF_RIDX + 128;        // 128 B
constexpr size_t OFF_BSUM = OFF_RWT + 128;
constexpr size_t OFF_ZERO = OFF_BSUM + SZ_BSUM;   // 1024 B zero page
constexpr size_t OFF_H = OFF_ZERO + 1024;

extern "C" void kernel_launch(void* const* d_in, const int* in_sizes, int n_in,
                              void* d_out, int out_size, void* d_ws, size_t ws_size,
                              hipStream_t stream) {
  const float* x = (const float*)d_in[0];
  const float* router_w = (const float*)d_in[1];
  const float* router_b = (const float*)d_in[2];
  const float* shared_w = (const float*)d_in[3];
  const float* shared_scale = (const float*)d_in[4];
  const float* shared_bias = (const float*)d_in[5];
  const float* w1 = (const float*)d_in[6];
  const float* bn1_scale = (const float*)d_in[7];
  const float* bn1_bias = (const float*)d_in[8];
  const float* w2 = (const float*)d_in[9];
  const float* bn2_scale = (const float*)d_in[10];
  const float* bn2_bias = (const float*)d_in[11];
  float* out = (float*)d_out;
  char* ws = (char*)d_ws;

  bf16* xT = (bf16*)(ws + OFF_XT);
  bf16* w1b = (bf16*)(ws + OFF_W1B);
  bf16* w2b = (bf16*)(ws + OFF_W2B);
  bf16* wshb = (bf16*)(ws + OFF_WSHB);
  float* pooled = (float*)(ws + OFF_POOL);
  int* ridx = (int*)(ws + OFF_RIDX);
  float* rwt = (float*)(ws + OFF_RWT);
  float* bsum = (float*)(ws + OFF_BSUM);
  bf16* zp = (bf16*)(ws + OFF_ZERO);
  bf16* h = (bf16*)(ws + OFF_H);

  hipMemsetAsync(ws + OFF_POOL, 0, SZ_POOL, stream);
  hipMemsetAsync(ws + OFF_ZERO, 0, 1024, stream);

  xT_kernel<<<dim3(49, 4, 16), 256, 0, stream>>>(x, xT, pooled);
  w1cvt_kernel<<<E_ * HID_, 256, 0, stream>>>(w1, bn1_scale, w1b);
  w2cvt_kernel<<<(E_ * O_ * HID_) / 256, 256, 0, stream>>>(w2, bn2_scale, w2b);
  wshcvt_kernel<<<(O_ * C_) / 256, 256, 0, stream>>>(shared_w, shared_scale, wshb);
  router_kernel<<<1, 256, 0, stream>>>(pooled, router_w, router_b, bn2_bias, ridx, rwt, bsum);
  conv1_kernel<<<832, 512, 0, stream>>>(xT, w1b, bn1_bias, ridx, rwt, zp, h);
  combine_kernel<<<208, 512, 0, stream>>>(xT, h, wshb, w2b, shared_bias, bsum, ridx, x, zp, out);
}